// Round 5
// baseline (316.219 us; speedup 1.0000x reference)
//
#include <hip/hip_runtime.h>

#define N_NODES 10000
#define N_EDGES 320000
#define DIM_IN  256
#define DD      128
#define HH      4
#define HD      512
#define GG      64

// ---------------- CSR build ----------------
__global__ void hist_kernel(const int* __restrict__ dst, int* __restrict__ cnt) {
  int e = blockIdx.x * 256 + threadIdx.x;
  atomicAdd(&cnt[dst[e]], 1);
}

__global__ void scan_kernel(const int* __restrict__ cnt, int* __restrict__ row_off) {
  __shared__ int part[1024];
  int t = threadIdx.x;
  int base = t * 10;
  int s = 0;
#pragma unroll
  for (int i = 0; i < 10; i++) { int idx = base + i; if (idx < N_NODES) s += cnt[idx]; }
  part[t] = s;
  __syncthreads();
  for (int off = 1; off < 1024; off <<= 1) {
    int v = (t >= off) ? part[t - off] : 0;
    __syncthreads();
    part[t] += v;
    __syncthreads();
  }
  int run = part[t] - s;
  for (int i = 0; i < 10; i++) {
    int idx = base + i;
    if (idx < N_NODES) { row_off[idx] = run; run += cnt[idx]; }
  }
  if (t == 1023) row_off[N_NODES] = part[1023];
}

__global__ void scatter_kernel(const int* __restrict__ src, const int* __restrict__ dst,
                               const int* __restrict__ row_off,
                               int* __restrict__ fill, int* __restrict__ srcl) {
  int e = blockIdx.x * 256 + threadIdx.x;
  int d = dst[e];
  int pos = row_off[d] + atomicAdd(&fill[d], 1);
  srcl[pos] = src[e];
}

// ---------------- dual GEMM: C1 = A@B1+bias1, C2 = A@B2+bias2 ----------------
template <int K, int NCOL, int BM>
__global__ __launch_bounds__(256) void dual_gemm(
    const float* __restrict__ A,
    const float* __restrict__ B1, const float* __restrict__ bias1,
    const float* __restrict__ B2, const float* __restrict__ bias2,
    float* __restrict__ C1, float* __restrict__ C2, int M) {
  constexpr int MR = BM / 16;
  constexpr int NQ = (BM * 4 + 255) / 256;
  __shared__ float At[16][BM + 4];
  __shared__ float Bs[16][68];
  __shared__ float Bd[16][68];
  int t = threadIdx.x;
  int col0 = blockIdx.x * 64;
  int row0 = blockIdx.y * BM;
  int bk = t >> 4, bc = (t & 15) * 4;
  int tx = t & 15, ty = t >> 4;
  float acc1[MR][4] = {}, acc2[MR][4] = {};
  for (int k0 = 0; k0 < K; k0 += 16) {
    float4 aq[NQ];
#pragma unroll
    for (int qi = 0; qi < NQ; qi++) {
      int q = t + qi * 256;
      if (q < BM * 4) {
        int row = q >> 2, kc = (q & 3) * 4;
        aq[qi] = (row0 + row < M)
                     ? *(const float4*)(A + (size_t)(row0 + row) * K + k0 + kc)
                     : make_float4(0.f, 0.f, 0.f, 0.f);
      }
    }
    float4 b1v = *(const float4*)(B1 + (size_t)(k0 + bk) * NCOL + col0 + bc);
    float4 b2v = *(const float4*)(B2 + (size_t)(k0 + bk) * NCOL + col0 + bc);
    __syncthreads();
#pragma unroll
    for (int qi = 0; qi < NQ; qi++) {
      int q = t + qi * 256;
      if (q < BM * 4) {
        int row = q >> 2, kc = (q & 3) * 4;
        At[kc + 0][row] = aq[qi].x;
        At[kc + 1][row] = aq[qi].y;
        At[kc + 2][row] = aq[qi].z;
        At[kc + 3][row] = aq[qi].w;
      }
    }
    *(float4*)&Bs[bk][bc] = b1v;
    *(float4*)&Bd[bk][bc] = b2v;
    __syncthreads();
#pragma unroll
    for (int kk = 0; kk < 16; kk++) {
      float a[MR];
      if constexpr (MR == 8) {
        float4 x0 = *(const float4*)&At[kk][ty * 8];
        float4 x1 = *(const float4*)&At[kk][ty * 8 + 4];
        a[0] = x0.x; a[1] = x0.y; a[2] = x0.z; a[3] = x0.w;
        a[4] = x1.x; a[5] = x1.y; a[6] = x1.z; a[7] = x1.w;
      } else {
        float2 x0 = *(const float2*)&At[kk][ty * 2];
        a[0] = x0.x; a[1] = x0.y;
      }
      float4 br1 = *(const float4*)&Bs[kk][tx * 4];
      float4 br2 = *(const float4*)&Bd[kk][tx * 4];
      float b1r[4] = {br1.x, br1.y, br1.z, br1.w};
      float b2r[4] = {br2.x, br2.y, br2.z, br2.w};
#pragma unroll
      for (int i = 0; i < MR; i++)
#pragma unroll
        for (int j = 0; j < 4; j++) {
          acc1[i][j] = fmaf(a[i], b1r[j], acc1[i][j]);
          acc2[i][j] = fmaf(a[i], b2r[j], acc2[i][j]);
        }
    }
  }
#pragma unroll
  for (int i = 0; i < MR; i++) {
    int row = row0 + ty * MR + i;
    if (row < M) {
      float4 o1, o2;
      int cb = col0 + tx * 4;
      o1.x = acc1[i][0] + bias1[cb + 0]; o1.y = acc1[i][1] + bias1[cb + 1];
      o1.z = acc1[i][2] + bias1[cb + 2]; o1.w = acc1[i][3] + bias1[cb + 3];
      o2.x = acc2[i][0] + bias2[cb + 0]; o2.y = acc2[i][1] + bias2[cb + 1];
      o2.z = acc2[i][2] + bias2[cb + 2]; o2.w = acc2[i][3] + bias2[cb + 3];
      *(float4*)(C1 + (size_t)row * NCOL + cb) = o1;
      *(float4*)(C2 + (size_t)row * NCOL + cb) = o2;
    }
  }
}

// ---------------- layer 1 fused: wave per (node, head-pair), 4-deep pipeline ----
// 64 lanes = 2 heads x 32 lanes; lane covers float4 at head*128 + pos*4.
// One edge per wave-iteration; 4 edge rows in flight.
__global__ __launch_bounds__(256) void fused_gat1(
    const float* __restrict__ hs, const float* __restrict__ hd,
    const float* __restrict__ attn, const int* __restrict__ row_off,
    const int* __restrict__ srcl, float* __restrict__ out) {
  int t = threadIdx.x;
  int w = t >> 6, lane = t & 63;
  int v = blockIdx.x * 2 + (w >> 1);
  int head = (w & 1) * 2 + (lane >> 5);
  int pos = lane & 31;
  int off = head * 128 + pos * 4;
  int start = row_off[v];
  int deg = row_off[v + 1] - start;

  float4 a = *(const float4*)(attn + off);
  float4 hdv = *(const float4*)(hd + (size_t)v * HD + off);
  const float* hsl = hs + off;

  float4 acc = make_float4(0.f, 0.f, 0.f, 0.f);
  float ssum = 0.f;

  float4 c[4];
#pragma unroll
  for (int q = 0; q < 4; q++)
    if (q < deg) c[q] = *(const float4*)(hsl + (size_t)srcl[start + q] * HD);

  for (int i = 0; i < deg; i += 4) {
    int cnt = deg - i; cnt = cnt < 4 ? cnt : 4;
    float4 u[4];
#pragma unroll
    for (int q = 0; q < 4; q++) u[q] = c[q];
#pragma unroll
    for (int q = 0; q < 4; q++) {
      int nx = i + 4 + q;
      if (nx < deg) c[q] = *(const float4*)(hsl + (size_t)srcl[start + nx] * HD);
    }
#pragma unroll
    for (int q = 0; q < 4; q++) {
      if (q < cnt) {
        float e0 = u[q].x + hdv.x; e0 = fmaxf(e0, 0.2f * e0);
        float e1 = u[q].y + hdv.y; e1 = fmaxf(e1, 0.2f * e1);
        float e2 = u[q].z + hdv.z; e2 = fmaxf(e2, 0.2f * e2);
        float e3 = u[q].w + hdv.w; e3 = fmaxf(e3, 0.2f * e3);
        float part = fmaf(e0, a.x, fmaf(e1, a.y, fmaf(e2, a.z, e3 * a.w)));
#pragma unroll
        for (int k = 1; k < 32; k <<= 1) part += __shfl_xor(part, k);
        float wg = __expf(part);
        ssum += wg;
        acc.x = fmaf(wg, u[q].x, acc.x);
        acc.y = fmaf(wg, u[q].y, acc.y);
        acc.z = fmaf(wg, u[q].z, acc.z);
        acc.w = fmaf(wg, u[q].w, acc.w);
      }
    }
  }
  float inv = ssum > 0.f ? 1.f / ssum : 0.f;
  *(float4*)(out + (size_t)v * HD + off) =
      make_float4(acc.x * inv, acc.y * inv, acc.z * inv, acc.w * inv);
}

// ---------------- layer 2 fused: wave per node, 4 x 16-lane groups, 2-deep -----
__global__ __launch_bounds__(256) void fused_gat2(
    const float* __restrict__ hs, const float* __restrict__ hd,
    const float* __restrict__ attn, const int* __restrict__ row_off,
    const int* __restrict__ srcl, float* __restrict__ out) {
  int t = threadIdx.x;
  int w = t >> 6, lane = t & 63, grp = lane >> 4, sl = lane & 15;
  int v = blockIdx.x * 4 + w;
  int start = row_off[v];
  int deg = row_off[v + 1] - start;

  const float* ap = attn + sl * 8;
  const float* hp = hd + (size_t)v * DD + sl * 8;
  float4 a0 = *(const float4*)ap, a1 = *(const float4*)(ap + 4);
  float4 g0 = *(const float4*)hp, g1 = *(const float4*)(hp + 4);
  float areg[8] = {a0.x, a0.y, a0.z, a0.w, a1.x, a1.y, a1.z, a1.w};
  float hdreg[8] = {g0.x, g0.y, g0.z, g0.w, g1.x, g1.y, g1.z, g1.w};
  const float* hsl = hs + sl * 8;

  float ssum = 0.f;
  float acc[8] = {0.f, 0.f, 0.f, 0.f, 0.f, 0.f, 0.f, 0.f};

  // 2-deep pipeline per group: edges grp + 4k
  float4 c0a = {0,0,0,0}, c0b = {0,0,0,0}, c1a = {0,0,0,0}, c1b = {0,0,0,0};
  if (grp < deg) { const float* p = hsl + (size_t)srcl[start + grp] * DD; c0a = *(const float4*)p; c0b = *(const float4*)(p + 4); }
  if (grp + 4 < deg) { const float* p = hsl + (size_t)srcl[start + grp + 4] * DD; c1a = *(const float4*)p; c1b = *(const float4*)(p + 4); }

  for (int i = grp; i < deg; i += 8) {
    float u0[8] = {c0a.x, c0a.y, c0a.z, c0a.w, c0b.x, c0b.y, c0b.z, c0b.w};
    float u1[8] = {c1a.x, c1a.y, c1a.z, c1a.w, c1b.x, c1b.y, c1b.z, c1b.w};
    bool have1 = (i + 4) < deg;
    if (i + 8 < deg) { const float* p = hsl + (size_t)srcl[start + i + 8] * DD; c0a = *(const float4*)p; c0b = *(const float4*)(p + 4); }
    if (i + 12 < deg) { const float* p = hsl + (size_t)srcl[start + i + 12] * DD; c1a = *(const float4*)p; c1b = *(const float4*)(p + 4); }
    float part0 = 0.f, part1 = 0.f;
#pragma unroll
    for (int j = 0; j < 8; j++) {
      float e0 = u0[j] + hdreg[j]; e0 = fmaxf(e0, 0.2f * e0);
      part0 = fmaf(e0, areg[j], part0);
      float e1 = u1[j] + hdreg[j]; e1 = fmaxf(e1, 0.2f * e1);
      part1 = fmaf(e1, areg[j], part1);
    }
#pragma unroll
    for (int k = 1; k < 16; k <<= 1) {
      part0 += __shfl_xor(part0, k);
      part1 += __shfl_xor(part1, k);
    }
    float wg0 = __expf(part0);
    float wg1 = have1 ? __expf(part1) : 0.f;
    ssum += wg0 + wg1;
#pragma unroll
    for (int j = 0; j < 8; j++)
      acc[j] = fmaf(wg0, u0[j], fmaf(wg1, u1[j], acc[j]));
  }
  // merge 4 groups within the wave
#pragma unroll
  for (int j = 0; j < 8; j++) {
    acc[j] += __shfl_xor(acc[j], 16);
    acc[j] += __shfl_xor(acc[j], 32);
  }
  ssum += __shfl_xor(ssum, 16);
  ssum += __shfl_xor(ssum, 32);
  float inv = ssum > 0.f ? 1.f / ssum : 0.f;
  if (lane < 16) {
    float* op = out + (size_t)v * DD + sl * 8;
    *(float4*)op = make_float4(acc[0] * inv, acc[1] * inv, acc[2] * inv, acc[3] * inv);
    *(float4*)(op + 4) = make_float4(acc[4] * inv, acc[5] * inv, acc[6] * inv, acc[7] * inv);
  }
}

// ---------------- pooling (binary search on sorted gid) + readout MLP ----------
__global__ __launch_bounds__(128) void final_kernel(
    const float* __restrict__ h2, const int* __restrict__ gid,
    const float* __restrict__ Wr1, const float* __restrict__ br1,
    const float* __restrict__ Wr2, const float* __restrict__ br2,
    float* __restrict__ out) {
  int g = blockIdx.x, t = threadIdx.x;
  int a, b;
  { int l = 0, h = N_NODES; while (l < h) { int m = (l + h) >> 1; if (gid[m] < g) l = m + 1; else h = m; } a = l; }
  { int l = a, h = N_NODES; while (l < h) { int m = (l + h) >> 1; if (gid[m] < g + 1) l = m + 1; else h = m; } b = l; }
  float s0 = 0.f, s1 = 0.f, s2 = 0.f, s3 = 0.f;
  int v = a;
  for (; v + 3 < b; v += 4) {
    s0 += h2[(size_t)(v + 0) * DD + t];
    s1 += h2[(size_t)(v + 1) * DD + t];
    s2 += h2[(size_t)(v + 2) * DD + t];
    s3 += h2[(size_t)(v + 3) * DD + t];
  }
  for (; v < b; v++) s0 += h2[(size_t)v * DD + t];
  __shared__ float hgn[128];
  float cnt = (float)(b - a);
  hgn[t] = ((s0 + s1) + (s2 + s3)) / fmaxf(cnt, 1.f);
  __syncthreads();
  if (t < 64) {
    float r = br1[t];
#pragma unroll 8
    for (int k = 0; k < 128; k++) r = fmaf(hgn[k], Wr1[k * 64 + t], r);
    r = fmaxf(r, 0.f);
    float p = r * Wr2[t];
#pragma unroll
    for (int k = 1; k < 64; k <<= 1) p += __shfl_xor(p, k);
    if (t == 0) out[g] = p + br2[0];
  }
}

extern "C" void kernel_launch(void* const* d_in, const int* in_sizes, int n_in,
                              void* d_out, int out_size, void* d_ws, size_t ws_size,
                              hipStream_t stream) {
  (void)in_sizes; (void)n_in; (void)out_size; (void)ws_size;
  const float* x     = (const float*)d_in[0];
  const float* W1s   = (const float*)d_in[1];
  const float* b1s   = (const float*)d_in[2];
  const float* W1d   = (const float*)d_in[3];
  const float* b1d   = (const float*)d_in[4];
  const float* attn1 = (const float*)d_in[5];
  const float* W2s   = (const float*)d_in[6];
  const float* b2s   = (const float*)d_in[7];
  const float* W2d   = (const float*)d_in[8];
  const float* b2d   = (const float*)d_in[9];
  const float* attn2 = (const float*)d_in[10];
  const float* Wr1   = (const float*)d_in[11];
  const float* br1   = (const float*)d_in[12];
  const float* Wr2   = (const float*)d_in[13];
  const float* br2   = (const float*)d_in[14];
  const int* src     = (const int*)d_in[15];
  const int* dst     = (const int*)d_in[16];
  const int* gid     = (const int*)d_in[17];
  float* out = (float*)d_out;

  char* ws = (char*)d_ws;
  float* hs1     = (float*)(ws + 0);          // N*512 f32
  float* hd1     = (float*)(ws + 20480000);   // N*512 f32
  float* h1      = (float*)(ws + 40960000);   // N*512 f32
  int*   srcl    = (int*)(ws + 61440000);     // E int
  int*   row_off = (int*)(ws + 62720000);     // (N+1) int
  int*   cnt     = (int*)(ws + 62760448);     // N int
  int*   fill    = (int*)(ws + 62800448);     // N int
  float* hs2 = hs1;
  float* hd2 = hd1;
  float* h2  = h1;

  hipMemsetAsync(cnt, 0, 2 * N_NODES * 4, stream);

  hist_kernel<<<N_EDGES / 256, 256, 0, stream>>>(dst, cnt);
  scan_kernel<<<1, 1024, 0, stream>>>(cnt, row_off);
  scatter_kernel<<<N_EDGES / 256, 256, 0, stream>>>(src, dst, row_off, fill, srcl);

  dual_gemm<DIM_IN, HD, 128><<<dim3(HD / 64, (N_NODES + 127) / 128), 256, 0, stream>>>(
      x, W1s, b1s, W1d, b1d, hs1, hd1, N_NODES);
  fused_gat1<<<(N_NODES + 1) / 2, 256, 0, stream>>>(hs1, hd1, attn1, row_off, srcl, h1);

  dual_gemm<HD, DD, 32><<<dim3(DD / 64, (N_NODES + 31) / 32), 256, 0, stream>>>(
      h1, W2s, b2s, W2d, b2d, hs2, hd2, N_NODES);
  fused_gat2<<<(N_NODES + 3) / 4, 256, 0, stream>>>(hs2, hd2, attn2, row_off, srcl, h2);

  final_kernel<<<GG, 128, 0, stream>>>(h2, gid, Wr1, br1, Wr2, br2, out);
}

// Round 6
// 306.419 us; speedup vs baseline: 1.0320x; 1.0320x over previous
//
#include <hip/hip_runtime.h>

#define N_NODES 10000
#define N_EDGES 320000
#define DIM_IN  256
#define DD      128
#define HH      4
#define HD      512
#define GG      64

// ---------------- CSR build ----------------
__global__ void hist_kernel(const int* __restrict__ dst, int* __restrict__ cnt) {
  int e = blockIdx.x * 256 + threadIdx.x;
  atomicAdd(&cnt[dst[e]], 1);
}

__global__ void scan_kernel(const int* __restrict__ cnt, int* __restrict__ row_off) {
  __shared__ int part[1024];
  int t = threadIdx.x;
  int base = t * 10;
  int s = 0;
#pragma unroll
  for (int i = 0; i < 10; i++) { int idx = base + i; if (idx < N_NODES) s += cnt[idx]; }
  part[t] = s;
  __syncthreads();
  for (int off = 1; off < 1024; off <<= 1) {
    int v = (t >= off) ? part[t - off] : 0;
    __syncthreads();
    part[t] += v;
    __syncthreads();
  }
  int run = part[t] - s;
  for (int i = 0; i < 10; i++) {
    int idx = base + i;
    if (idx < N_NODES) { row_off[idx] = run; run += cnt[idx]; }
  }
  if (t == 1023) row_off[N_NODES] = part[1023];
}

__global__ void scatter_kernel(const int* __restrict__ src, const int* __restrict__ dst,
                               const int* __restrict__ row_off,
                               int* __restrict__ fill, int* __restrict__ srcl) {
  int e = blockIdx.x * 256 + threadIdx.x;
  int d = dst[e];
  int pos = row_off[d] + atomicAdd(&fill[d], 1);
  srcl[pos] = src[e];
}

// ---------------- dual GEMM: C1 = A@B1+bias1, C2 = A@B2+bias2 ----------------
template <int K, int NCOL, int BM>
__global__ __launch_bounds__(256) void dual_gemm(
    const float* __restrict__ A,
    const float* __restrict__ B1, const float* __restrict__ bias1,
    const float* __restrict__ B2, const float* __restrict__ bias2,
    float* __restrict__ C1, float* __restrict__ C2, int M) {
  constexpr int MR = BM / 16;
  constexpr int NQ = (BM * 4 + 255) / 256;
  __shared__ float At[16][BM + 4];
  __shared__ float Bs[16][68];
  __shared__ float Bd[16][68];
  int t = threadIdx.x;
  int col0 = blockIdx.x * 64;
  int row0 = blockIdx.y * BM;
  int bk = t >> 4, bc = (t & 15) * 4;
  int tx = t & 15, ty = t >> 4;
  float acc1[MR][4] = {}, acc2[MR][4] = {};
  for (int k0 = 0; k0 < K; k0 += 16) {
    float4 aq[NQ];
#pragma unroll
    for (int qi = 0; qi < NQ; qi++) {
      int q = t + qi * 256;
      if (q < BM * 4) {
        int row = q >> 2, kc = (q & 3) * 4;
        aq[qi] = (row0 + row < M)
                     ? *(const float4*)(A + (size_t)(row0 + row) * K + k0 + kc)
                     : make_float4(0.f, 0.f, 0.f, 0.f);
      }
    }
    float4 b1v = *(const float4*)(B1 + (size_t)(k0 + bk) * NCOL + col0 + bc);
    float4 b2v = *(const float4*)(B2 + (size_t)(k0 + bk) * NCOL + col0 + bc);
    __syncthreads();
#pragma unroll
    for (int qi = 0; qi < NQ; qi++) {
      int q = t + qi * 256;
      if (q < BM * 4) {
        int row = q >> 2, kc = (q & 3) * 4;
        At[kc + 0][row] = aq[qi].x;
        At[kc + 1][row] = aq[qi].y;
        At[kc + 2][row] = aq[qi].z;
        At[kc + 3][row] = aq[qi].w;
      }
    }
    *(float4*)&Bs[bk][bc] = b1v;
    *(float4*)&Bd[bk][bc] = b2v;
    __syncthreads();
#pragma unroll
    for (int kk = 0; kk < 16; kk++) {
      float a[MR];
      if constexpr (MR == 8) {
        float4 x0 = *(const float4*)&At[kk][ty * 8];
        float4 x1 = *(const float4*)&At[kk][ty * 8 + 4];
        a[0] = x0.x; a[1] = x0.y; a[2] = x0.z; a[3] = x0.w;
        a[4] = x1.x; a[5] = x1.y; a[6] = x1.z; a[7] = x1.w;
      } else {
        float2 x0 = *(const float2*)&At[kk][ty * 2];
        a[0] = x0.x; a[1] = x0.y;
      }
      float4 br1 = *(const float4*)&Bs[kk][tx * 4];
      float4 br2 = *(const float4*)&Bd[kk][tx * 4];
      float b1r[4] = {br1.x, br1.y, br1.z, br1.w};
      float b2r[4] = {br2.x, br2.y, br2.z, br2.w};
#pragma unroll
      for (int i = 0; i < MR; i++)
#pragma unroll
        for (int j = 0; j < 4; j++) {
          acc1[i][j] = fmaf(a[i], b1r[j], acc1[i][j]);
          acc2[i][j] = fmaf(a[i], b2r[j], acc2[i][j]);
        }
    }
  }
#pragma unroll
  for (int i = 0; i < MR; i++) {
    int row = row0 + ty * MR + i;
    if (row < M) {
      float4 o1, o2;
      int cb = col0 + tx * 4;
      o1.x = acc1[i][0] + bias1[cb + 0]; o1.y = acc1[i][1] + bias1[cb + 1];
      o1.z = acc1[i][2] + bias1[cb + 2]; o1.w = acc1[i][3] + bias1[cb + 3];
      o2.x = acc2[i][0] + bias2[cb + 0]; o2.y = acc2[i][1] + bias2[cb + 1];
      o2.z = acc2[i][2] + bias2[cb + 2]; o2.w = acc2[i][3] + bias2[cb + 3];
      *(float4*)(C1 + (size_t)row * NCOL + cb) = o1;
      *(float4*)(C2 + (size_t)row * NCOL + cb) = o2;
    }
  }
}

// ---------------- layer 1 fused: wave per node, readlane indices, 4-deep -------
// lane covers 8 contiguous floats (head = lane>>4); 16-lane head-group reduce.
__global__ __launch_bounds__(256) void fused_gat1(
    const float* __restrict__ hs, const float* __restrict__ hd,
    const float* __restrict__ attn, const int* __restrict__ row_off,
    const int* __restrict__ srcl, float* __restrict__ out) {
  int t = threadIdx.x;
  int w = t >> 6, lane = t & 63;
  int v = blockIdx.x * 4 + w;
  int start = row_off[v];
  int deg = row_off[v + 1] - start;

  const float* ap = attn + lane * 8;
  const float* hp = hd + (size_t)v * HD + lane * 8;
  float4 a0 = *(const float4*)ap, a1 = *(const float4*)(ap + 4);
  float4 g0 = *(const float4*)hp, g1 = *(const float4*)(hp + 4);
  float areg[8] = {a0.x, a0.y, a0.z, a0.w, a1.x, a1.y, a1.z, a1.w};
  float hdreg[8] = {g0.x, g0.y, g0.z, g0.w, g1.x, g1.y, g1.z, g1.w};
  const float* hsl = hs + lane * 8;

  float ssum = 0.f;
  float acc[8] = {0.f, 0.f, 0.f, 0.f, 0.f, 0.f, 0.f, 0.f};

  for (int base = 0; base < deg; base += 64) {
    int nc = deg - base; nc = nc < 64 ? nc : 64;
    // one coalesced index load for the whole chunk
    int myidx = (lane < nc) ? srcl[start + base + lane] : 0;

    float4 c0q0, c1q0, c0q1, c1q1, c0q2, c1q2, c0q3, c1q3;
    if (0 < nc) { const float* p = hsl + (size_t)__builtin_amdgcn_readlane(myidx, 0) * HD; c0q0 = *(const float4*)p; c1q0 = *(const float4*)(p + 4); }
    if (1 < nc) { const float* p = hsl + (size_t)__builtin_amdgcn_readlane(myidx, 1) * HD; c0q1 = *(const float4*)p; c1q1 = *(const float4*)(p + 4); }
    if (2 < nc) { const float* p = hsl + (size_t)__builtin_amdgcn_readlane(myidx, 2) * HD; c0q2 = *(const float4*)p; c1q2 = *(const float4*)(p + 4); }
    if (3 < nc) { const float* p = hsl + (size_t)__builtin_amdgcn_readlane(myidx, 3) * HD; c0q3 = *(const float4*)p; c1q3 = *(const float4*)(p + 4); }

    for (int i0 = 0; i0 < nc; i0 += 4) {
#define GAT1_STEP(Q, C0, C1)                                                          \
      if (i0 + Q < nc) {                                                              \
        float u[8] = {C0.x, C0.y, C0.z, C0.w, C1.x, C1.y, C1.z, C1.w};                \
        int nx = i0 + 4 + Q;                                                          \
        if (nx < nc) {                                                                \
          const float* p = hsl + (size_t)__builtin_amdgcn_readlane(myidx, nx) * HD;   \
          C0 = *(const float4*)p; C1 = *(const float4*)(p + 4);                       \
        }                                                                             \
        float part = 0.f;                                                             \
        _Pragma("unroll")                                                             \
        for (int j = 0; j < 8; j++) {                                                 \
          float e = u[j] + hdreg[j];                                                  \
          e = fmaxf(e, 0.2f * e);                                                     \
          part = fmaf(e, areg[j], part);                                              \
        }                                                                             \
        _Pragma("unroll")                                                             \
        for (int k = 1; k < 16; k <<= 1) part += __shfl_xor(part, k);                 \
        float wg = __expf(part);                                                      \
        ssum += wg;                                                                   \
        _Pragma("unroll")                                                             \
        for (int j = 0; j < 8; j++) acc[j] = fmaf(wg, u[j], acc[j]);                  \
      }
      GAT1_STEP(0, c0q0, c1q0)
      GAT1_STEP(1, c0q1, c1q1)
      GAT1_STEP(2, c0q2, c1q2)
      GAT1_STEP(3, c0q3, c1q3)
#undef GAT1_STEP
    }
  }
  float inv = ssum > 0.f ? 1.f / ssum : 0.f;
  float* op = out + (size_t)v * HD + lane * 8;
  *(float4*)op = make_float4(acc[0] * inv, acc[1] * inv, acc[2] * inv, acc[3] * inv);
  *(float4*)(op + 4) = make_float4(acc[4] * inv, acc[5] * inv, acc[6] * inv, acc[7] * inv);
}

// ---------------- layer 2 fused: wave per node, 4 x 16-lane groups, 2-deep -----
__global__ __launch_bounds__(256) void fused_gat2(
    const float* __restrict__ hs, const float* __restrict__ hd,
    const float* __restrict__ attn, const int* __restrict__ row_off,
    const int* __restrict__ srcl, float* __restrict__ out) {
  int t = threadIdx.x;
  int w = t >> 6, lane = t & 63, grp = lane >> 4, sl = lane & 15;
  int v = blockIdx.x * 4 + w;
  int start = row_off[v];
  int deg = row_off[v + 1] - start;

  const float* ap = attn + sl * 8;
  const float* hp = hd + (size_t)v * DD + sl * 8;
  float4 a0 = *(const float4*)ap, a1 = *(const float4*)(ap + 4);
  float4 g0 = *(const float4*)hp, g1 = *(const float4*)(hp + 4);
  float areg[8] = {a0.x, a0.y, a0.z, a0.w, a1.x, a1.y, a1.z, a1.w};
  float hdreg[8] = {g0.x, g0.y, g0.z, g0.w, g1.x, g1.y, g1.z, g1.w};
  const float* hsl = hs + sl * 8;

  float ssum = 0.f;
  float acc[8] = {0.f, 0.f, 0.f, 0.f, 0.f, 0.f, 0.f, 0.f};

  float4 c0a = {0,0,0,0}, c0b = {0,0,0,0}, c1a = {0,0,0,0}, c1b = {0,0,0,0};
  if (grp < deg) { const float* p = hsl + (size_t)srcl[start + grp] * DD; c0a = *(const float4*)p; c0b = *(const float4*)(p + 4); }
  if (grp + 4 < deg) { const float* p = hsl + (size_t)srcl[start + grp + 4] * DD; c1a = *(const float4*)p; c1b = *(const float4*)(p + 4); }

  for (int i = grp; i < deg; i += 8) {
    float u0[8] = {c0a.x, c0a.y, c0a.z, c0a.w, c0b.x, c0b.y, c0b.z, c0b.w};
    float u1[8] = {c1a.x, c1a.y, c1a.z, c1a.w, c1b.x, c1b.y, c1b.z, c1b.w};
    bool have1 = (i + 4) < deg;
    if (i + 8 < deg) { const float* p = hsl + (size_t)srcl[start + i + 8] * DD; c0a = *(const float4*)p; c0b = *(const float4*)(p + 4); }
    if (i + 12 < deg) { const float* p = hsl + (size_t)srcl[start + i + 12] * DD; c1a = *(const float4*)p; c1b = *(const float4*)(p + 4); }
    float part0 = 0.f, part1 = 0.f;
#pragma unroll
    for (int j = 0; j < 8; j++) {
      float e0 = u0[j] + hdreg[j]; e0 = fmaxf(e0, 0.2f * e0);
      part0 = fmaf(e0, areg[j], part0);
      float e1 = u1[j] + hdreg[j]; e1 = fmaxf(e1, 0.2f * e1);
      part1 = fmaf(e1, areg[j], part1);
    }
#pragma unroll
    for (int k = 1; k < 16; k <<= 1) {
      part0 += __shfl_xor(part0, k);
      part1 += __shfl_xor(part1, k);
    }
    float wg0 = __expf(part0);
    float wg1 = have1 ? __expf(part1) : 0.f;
    ssum += wg0 + wg1;
#pragma unroll
    for (int j = 0; j < 8; j++)
      acc[j] = fmaf(wg0, u0[j], fmaf(wg1, u1[j], acc[j]));
  }
#pragma unroll
  for (int j = 0; j < 8; j++) {
    acc[j] += __shfl_xor(acc[j], 16);
    acc[j] += __shfl_xor(acc[j], 32);
  }
  ssum += __shfl_xor(ssum, 16);
  ssum += __shfl_xor(ssum, 32);
  float inv = ssum > 0.f ? 1.f / ssum : 0.f;
  if (lane < 16) {
    float* op = out + (size_t)v * DD + sl * 8;
    *(float4*)op = make_float4(acc[0] * inv, acc[1] * inv, acc[2] * inv, acc[3] * inv);
    *(float4*)(op + 4) = make_float4(acc[4] * inv, acc[5] * inv, acc[6] * inv, acc[7] * inv);
  }
}

// ---------------- pooling (binary search on sorted gid) + readout MLP ----------
__global__ __launch_bounds__(128) void final_kernel(
    const float* __restrict__ h2, const int* __restrict__ gid,
    const float* __restrict__ Wr1, const float* __restrict__ br1,
    const float* __restrict__ Wr2, const float* __restrict__ br2,
    float* __restrict__ out) {
  int g = blockIdx.x, t = threadIdx.x;
  int a, b;
  { int l = 0, h = N_NODES; while (l < h) { int m = (l + h) >> 1; if (gid[m] < g) l = m + 1; else h = m; } a = l; }
  { int l = a, h = N_NODES; while (l < h) { int m = (l + h) >> 1; if (gid[m] < g + 1) l = m + 1; else h = m; } b = l; }
  float s0 = 0.f, s1 = 0.f, s2 = 0.f, s3 = 0.f;
  int v = a;
  for (; v + 3 < b; v += 4) {
    s0 += h2[(size_t)(v + 0) * DD + t];
    s1 += h2[(size_t)(v + 1) * DD + t];
    s2 += h2[(size_t)(v + 2) * DD + t];
    s3 += h2[(size_t)(v + 3) * DD + t];
  }
  for (; v < b; v++) s0 += h2[(size_t)v * DD + t];
  __shared__ float hgn[128];
  float cnt = (float)(b - a);
  hgn[t] = ((s0 + s1) + (s2 + s3)) / fmaxf(cnt, 1.f);
  __syncthreads();
  if (t < 64) {
    float r = br1[t];
#pragma unroll 8
    for (int k = 0; k < 128; k++) r = fmaf(hgn[k], Wr1[k * 64 + t], r);
    r = fmaxf(r, 0.f);
    float p = r * Wr2[t];
#pragma unroll
    for (int k = 1; k < 64; k <<= 1) p += __shfl_xor(p, k);
    if (t == 0) out[g] = p + br2[0];
  }
}

extern "C" void kernel_launch(void* const* d_in, const int* in_sizes, int n_in,
                              void* d_out, int out_size, void* d_ws, size_t ws_size,
                              hipStream_t stream) {
  (void)in_sizes; (void)n_in; (void)out_size; (void)ws_size;
  const float* x     = (const float*)d_in[0];
  const float* W1s   = (const float*)d_in[1];
  const float* b1s   = (const float*)d_in[2];
  const float* W1d   = (const float*)d_in[3];
  const float* b1d   = (const float*)d_in[4];
  const float* attn1 = (const float*)d_in[5];
  const float* W2s   = (const float*)d_in[6];
  const float* b2s   = (const float*)d_in[7];
  const float* W2d   = (const float*)d_in[8];
  const float* b2d   = (const float*)d_in[9];
  const float* attn2 = (const float*)d_in[10];
  const float* Wr1   = (const float*)d_in[11];
  const float* br1   = (const float*)d_in[12];
  const float* Wr2   = (const float*)d_in[13];
  const float* br2   = (const float*)d_in[14];
  const int* src     = (const int*)d_in[15];
  const int* dst     = (const int*)d_in[16];
  const int* gid     = (const int*)d_in[17];
  float* out = (float*)d_out;

  char* ws = (char*)d_ws;
  float* hs1     = (float*)(ws + 0);          // N*512 f32
  float* hd1     = (float*)(ws + 20480000);   // N*512 f32
  float* h1      = (float*)(ws + 40960000);   // N*512 f32
  int*   srcl    = (int*)(ws + 61440000);     // E int
  int*   row_off = (int*)(ws + 62720000);     // (N+1) int
  int*   cnt     = (int*)(ws + 62760448);     // N int
  int*   fill    = (int*)(ws + 62800448);     // N int
  float* hs2 = hs1;
  float* hd2 = hd1;
  float* h2  = h1;

  hipMemsetAsync(cnt, 0, 2 * N_NODES * 4, stream);

  hist_kernel<<<N_EDGES / 256, 256, 0, stream>>>(dst, cnt);
  scan_kernel<<<1, 1024, 0, stream>>>(cnt, row_off);
  scatter_kernel<<<N_EDGES / 256, 256, 0, stream>>>(src, dst, row_off, fill, srcl);

  dual_gemm<DIM_IN, HD, 128><<<dim3(HD / 64, (N_NODES + 127) / 128), 256, 0, stream>>>(
      x, W1s, b1s, W1d, b1d, hs1, hd1, N_NODES);
  fused_gat1<<<(N_NODES + 3) / 4, 256, 0, stream>>>(hs1, hd1, attn1, row_off, srcl, h1);

  dual_gemm<HD, DD, 32><<<dim3(DD / 64, (N_NODES + 31) / 32), 256, 0, stream>>>(
      h1, W2s, b2s, W2d, b2d, hs2, hd2, N_NODES);
  fused_gat2<<<(N_NODES + 3) / 4, 256, 0, stream>>>(hs2, hd2, attn2, row_off, srcl, h2);

  final_kernel<<<GG, 128, 0, stream>>>(h2, gid, Wr1, br1, Wr2, br2, out);
}

// Round 8
// 295.159 us; speedup vs baseline: 1.0713x; 1.0382x over previous
//
#include <hip/hip_runtime.h>

#define N_NODES 10000
#define N_EDGES 320000
#define DIM_IN  256
#define DD      128
#define HH      4
#define HD      512
#define GG      64

// ---------------- CSR build ----------------
__global__ void hist_kernel(const int* __restrict__ dst, int* __restrict__ cnt) {
  int e = blockIdx.x * 256 + threadIdx.x;
  atomicAdd(&cnt[dst[e]], 1);
}

__global__ void scan_kernel(const int* __restrict__ cnt, int* __restrict__ row_off) {
  __shared__ int part[1024];
  int t = threadIdx.x;
  int base = t * 10;
  int s = 0;
#pragma unroll
  for (int i = 0; i < 10; i++) { int idx = base + i; if (idx < N_NODES) s += cnt[idx]; }
  part[t] = s;
  __syncthreads();
  for (int off = 1; off < 1024; off <<= 1) {
    int v = (t >= off) ? part[t - off] : 0;
    __syncthreads();
    part[t] += v;
    __syncthreads();
  }
  int run = part[t] - s;
  for (int i = 0; i < 10; i++) {
    int idx = base + i;
    if (idx < N_NODES) { row_off[idx] = run; run += cnt[idx]; }
  }
  if (t == 1023) row_off[N_NODES] = part[1023];
}

__global__ void scatter_kernel(const int* __restrict__ src, const int* __restrict__ dst,
                               const int* __restrict__ row_off,
                               int* __restrict__ fill, int* __restrict__ srcl) {
  int e = blockIdx.x * 256 + threadIdx.x;
  int d = dst[e];
  int pos = row_off[d] + atomicAdd(&fill[d], 1);
  srcl[pos] = src[e];
}

// ---------------- dual GEMM: C1 = A@B1+bias1, C2 = A@B2+bias2 ----------------
template <int K, int NCOL, int BM>
__global__ __launch_bounds__(256) void dual_gemm(
    const float* __restrict__ A,
    const float* __restrict__ B1, const float* __restrict__ bias1,
    const float* __restrict__ B2, const float* __restrict__ bias2,
    float* __restrict__ C1, float* __restrict__ C2, int M) {
  constexpr int MR = BM / 16;
  constexpr int NQ = (BM * 4 + 255) / 256;
  __shared__ float At[16][BM + 4];
  __shared__ float Bs[16][68];
  __shared__ float Bd[16][68];
  int t = threadIdx.x;
  int col0 = blockIdx.x * 64;
  int row0 = blockIdx.y * BM;
  int bk = t >> 4, bc = (t & 15) * 4;
  int tx = t & 15, ty = t >> 4;
  float acc1[MR][4] = {}, acc2[MR][4] = {};
  for (int k0 = 0; k0 < K; k0 += 16) {
    float4 aq[NQ];
#pragma unroll
    for (int qi = 0; qi < NQ; qi++) {
      int q = t + qi * 256;
      if (q < BM * 4) {
        int row = q >> 2, kc = (q & 3) * 4;
        aq[qi] = (row0 + row < M)
                     ? *(const float4*)(A + (size_t)(row0 + row) * K + k0 + kc)
                     : make_float4(0.f, 0.f, 0.f, 0.f);
      }
    }
    float4 b1v = *(const float4*)(B1 + (size_t)(k0 + bk) * NCOL + col0 + bc);
    float4 b2v = *(const float4*)(B2 + (size_t)(k0 + bk) * NCOL + col0 + bc);
    __syncthreads();
#pragma unroll
    for (int qi = 0; qi < NQ; qi++) {
      int q = t + qi * 256;
      if (q < BM * 4) {
        int row = q >> 2, kc = (q & 3) * 4;
        At[kc + 0][row] = aq[qi].x;
        At[kc + 1][row] = aq[qi].y;
        At[kc + 2][row] = aq[qi].z;
        At[kc + 3][row] = aq[qi].w;
      }
    }
    *(float4*)&Bs[bk][bc] = b1v;
    *(float4*)&Bd[bk][bc] = b2v;
    __syncthreads();
#pragma unroll
    for (int kk = 0; kk < 16; kk++) {
      float a[MR];
      if constexpr (MR == 8) {
        float4 x0 = *(const float4*)&At[kk][ty * 8];
        float4 x1 = *(const float4*)&At[kk][ty * 8 + 4];
        a[0] = x0.x; a[1] = x0.y; a[2] = x0.z; a[3] = x0.w;
        a[4] = x1.x; a[5] = x1.y; a[6] = x1.z; a[7] = x1.w;
      } else {
        float2 x0 = *(const float2*)&At[kk][ty * 2];
        a[0] = x0.x; a[1] = x0.y;
      }
      float4 br1 = *(const float4*)&Bs[kk][tx * 4];
      float4 br2 = *(const float4*)&Bd[kk][tx * 4];
      float b1r[4] = {br1.x, br1.y, br1.z, br1.w};
      float b2r[4] = {br2.x, br2.y, br2.z, br2.w};
#pragma unroll
      for (int i = 0; i < MR; i++)
#pragma unroll
        for (int j = 0; j < 4; j++) {
          acc1[i][j] = fmaf(a[i], b1r[j], acc1[i][j]);
          acc2[i][j] = fmaf(a[i], b2r[j], acc2[i][j]);
        }
    }
  }
#pragma unroll
  for (int i = 0; i < MR; i++) {
    int row = row0 + ty * MR + i;
    if (row < M) {
      float4 o1, o2;
      int cb = col0 + tx * 4;
      o1.x = acc1[i][0] + bias1[cb + 0]; o1.y = acc1[i][1] + bias1[cb + 1];
      o1.z = acc1[i][2] + bias1[cb + 2]; o1.w = acc1[i][3] + bias1[cb + 3];
      o2.x = acc2[i][0] + bias2[cb + 0]; o2.y = acc2[i][1] + bias2[cb + 1];
      o2.z = acc2[i][2] + bias2[cb + 2]; o2.w = acc2[i][3] + bias2[cb + 3];
      *(float4*)(C1 + (size_t)row * NCOL + cb) = o1;
      *(float4*)(C2 + (size_t)row * NCOL + cb) = o2;
    }
  }
}

// ---------------- layer 1 fused: wave per (node, head-half) --------------------
// 20000 wave-items: W < N -> dims [0,256) (heads 0,1); W >= N -> dims [256,512).
// lane covers 4 floats; lanes 0-31 = one head (128 dims), lanes 32-63 = other.
// Wave-uniform edge loop (single edge per step), readlane chunk indices, 4-deep.
__global__ __launch_bounds__(256) void fused_gat1(
    const float* __restrict__ hs, const float* __restrict__ hd,
    const float* __restrict__ attn, const int* __restrict__ row_off,
    const int* __restrict__ srcl, float* __restrict__ out) {
  int t = threadIdx.x;
  int w = t >> 6, lane = t & 63;
  int W = blockIdx.x * 4 + w;           // 0..19999
  int half = (W >= N_NODES) ? 1 : 0;
  int v = W - half * N_NODES;
  int off = half * 256 + lane * 4;
  int start = row_off[v];
  int deg = row_off[v + 1] - start;

  float4 a = *(const float4*)(attn + off);
  float4 hdv = *(const float4*)(hd + (size_t)v * HD + off);
  const float* hsl = hs + off;

  float ssum = 0.f;
  float4 acc = make_float4(0.f, 0.f, 0.f, 0.f);

  for (int base = 0; base < deg; base += 64) {
    int nc = deg - base; nc = nc < 64 ? nc : 64;
    // one coalesced index load per 64-edge chunk
    int myidx = (lane < nc) ? srcl[start + base + lane] : 0;

    float4 c0 = {0,0,0,0}, c1 = {0,0,0,0}, c2 = {0,0,0,0}, c3 = {0,0,0,0};
    if (0 < nc) c0 = *(const float4*)(hsl + (size_t)__builtin_amdgcn_readlane(myidx, 0) * HD);
    if (1 < nc) c1 = *(const float4*)(hsl + (size_t)__builtin_amdgcn_readlane(myidx, 1) * HD);
    if (2 < nc) c2 = *(const float4*)(hsl + (size_t)__builtin_amdgcn_readlane(myidx, 2) * HD);
    if (3 < nc) c3 = *(const float4*)(hsl + (size_t)__builtin_amdgcn_readlane(myidx, 3) * HD);

    for (int i0 = 0; i0 < nc; i0 += 4) {
#define GAT1_STEP(Q, C)                                                               \
      if (i0 + Q < nc) {                                                              \
        float4 u = C;                                                                 \
        int nx = i0 + 4 + Q;                                                          \
        if (nx < nc)                                                                  \
          C = *(const float4*)(hsl + (size_t)__builtin_amdgcn_readlane(myidx, nx) * HD); \
        float e0 = u.x + hdv.x; e0 = fmaxf(e0, 0.2f * e0);                            \
        float e1 = u.y + hdv.y; e1 = fmaxf(e1, 0.2f * e1);                            \
        float e2 = u.z + hdv.z; e2 = fmaxf(e2, 0.2f * e2);                            \
        float e3 = u.w + hdv.w; e3 = fmaxf(e3, 0.2f * e3);                            \
        float part = fmaf(e0, a.x, fmaf(e1, a.y, fmaf(e2, a.z, e3 * a.w)));           \
        _Pragma("unroll")                                                             \
        for (int k = 1; k < 32; k <<= 1) part += __shfl_xor(part, k);                 \
        float wg = __expf(part);                                                      \
        ssum += wg;                                                                   \
        acc.x = fmaf(wg, u.x, acc.x);                                                 \
        acc.y = fmaf(wg, u.y, acc.y);                                                 \
        acc.z = fmaf(wg, u.z, acc.z);                                                 \
        acc.w = fmaf(wg, u.w, acc.w);                                                 \
      }
      GAT1_STEP(0, c0)
      GAT1_STEP(1, c1)
      GAT1_STEP(2, c2)
      GAT1_STEP(3, c3)
#undef GAT1_STEP
    }
  }
  float inv = ssum > 0.f ? 1.f / ssum : 0.f;
  *(float4*)(out + (size_t)v * HD + off) =
      make_float4(acc.x * inv, acc.y * inv, acc.z * inv, acc.w * inv);
}

// ---------------- layer 2 fused: wave per node, 4 x 16-lane groups, 2-deep -----
// (round-6 verified version, verbatim)
__global__ __launch_bounds__(256) void fused_gat2(
    const float* __restrict__ hs, const float* __restrict__ hd,
    const float* __restrict__ attn, const int* __restrict__ row_off,
    const int* __restrict__ srcl, float* __restrict__ out) {
  int t = threadIdx.x;
  int w = t >> 6, lane = t & 63, grp = lane >> 4, sl = lane & 15;
  int v = blockIdx.x * 4 + w;
  int start = row_off[v];
  int deg = row_off[v + 1] - start;

  const float* ap = attn + sl * 8;
  const float* hp = hd + (size_t)v * DD + sl * 8;
  float4 a0 = *(const float4*)ap, a1 = *(const float4*)(ap + 4);
  float4 g0 = *(const float4*)hp, g1 = *(const float4*)(hp + 4);
  float areg[8] = {a0.x, a0.y, a0.z, a0.w, a1.x, a1.y, a1.z, a1.w};
  float hdreg[8] = {g0.x, g0.y, g0.z, g0.w, g1.x, g1.y, g1.z, g1.w};
  const float* hsl = hs + sl * 8;

  float ssum = 0.f;
  float acc[8] = {0.f, 0.f, 0.f, 0.f, 0.f, 0.f, 0.f, 0.f};

  float4 c0a = {0,0,0,0}, c0b = {0,0,0,0}, c1a = {0,0,0,0}, c1b = {0,0,0,0};
  if (grp < deg) { const float* p = hsl + (size_t)srcl[start + grp] * DD; c0a = *(const float4*)p; c0b = *(const float4*)(p + 4); }
  if (grp + 4 < deg) { const float* p = hsl + (size_t)srcl[start + grp + 4] * DD; c1a = *(const float4*)p; c1b = *(const float4*)(p + 4); }

  for (int i = grp; i < deg; i += 8) {
    float u0[8] = {c0a.x, c0a.y, c0a.z, c0a.w, c0b.x, c0b.y, c0b.z, c0b.w};
    float u1[8] = {c1a.x, c1a.y, c1a.z, c1a.w, c1b.x, c1b.y, c1b.z, c1b.w};
    bool have1 = (i + 4) < deg;
    if (i + 8 < deg) { const float* p = hsl + (size_t)srcl[start + i + 8] * DD; c0a = *(const float4*)p; c0b = *(const float4*)(p + 4); }
    if (i + 12 < deg) { const float* p = hsl + (size_t)srcl[start + i + 12] * DD; c1a = *(const float4*)p; c1b = *(const float4*)(p + 4); }
    float part0 = 0.f, part1 = 0.f;
#pragma unroll
    for (int j = 0; j < 8; j++) {
      float e0 = u0[j] + hdreg[j]; e0 = fmaxf(e0, 0.2f * e0);
      part0 = fmaf(e0, areg[j], part0);
      float e1 = u1[j] + hdreg[j]; e1 = fmaxf(e1, 0.2f * e1);
      part1 = fmaf(e1, areg[j], part1);
    }
#pragma unroll
    for (int k = 1; k < 16; k <<= 1) {
      part0 += __shfl_xor(part0, k);
      part1 += __shfl_xor(part1, k);
    }
    float wg0 = __expf(part0);
    float wg1 = have1 ? __expf(part1) : 0.f;
    ssum += wg0 + wg1;
#pragma unroll
    for (int j = 0; j < 8; j++)
      acc[j] = fmaf(wg0, u0[j], fmaf(wg1, u1[j], acc[j]));
  }
#pragma unroll
  for (int j = 0; j < 8; j++) {
    acc[j] += __shfl_xor(acc[j], 16);
    acc[j] += __shfl_xor(acc[j], 32);
  }
  ssum += __shfl_xor(ssum, 16);
  ssum += __shfl_xor(ssum, 32);
  float inv = ssum > 0.f ? 1.f / ssum : 0.f;
  if (lane < 16) {
    float* op = out + (size_t)v * DD + sl * 8;
    *(float4*)op = make_float4(acc[0] * inv, acc[1] * inv, acc[2] * inv, acc[3] * inv);
    *(float4*)(op + 4) = make_float4(acc[4] * inv, acc[5] * inv, acc[6] * inv, acc[7] * inv);
  }
}

// ---------------- pooling (binary search on sorted gid) + readout MLP ----------
__global__ __launch_bounds__(128) void final_kernel(
    const float* __restrict__ h2, const int* __restrict__ gid,
    const float* __restrict__ Wr1, const float* __restrict__ br1,
    const float* __restrict__ Wr2, const float* __restrict__ br2,
    float* __restrict__ out) {
  int g = blockIdx.x, t = threadIdx.x;
  int a, b;
  { int l = 0, h = N_NODES; while (l < h) { int m = (l + h) >> 1; if (gid[m] < g) l = m + 1; else h = m; } a = l; }
  { int l = a, h = N_NODES; while (l < h) { int m = (l + h) >> 1; if (gid[m] < g + 1) l = m + 1; else h = m; } b = l; }
  float s0 = 0.f, s1 = 0.f, s2 = 0.f, s3 = 0.f;
  int v = a;
  for (; v + 3 < b; v += 4) {
    s0 += h2[(size_t)(v + 0) * DD + t];
    s1 += h2[(size_t)(v + 1) * DD + t];
    s2 += h2[(size_t)(v + 2) * DD + t];
    s3 += h2[(size_t)(v + 3) * DD + t];
  }
  for (; v < b; v++) s0 += h2[(size_t)v * DD + t];
  __shared__ float hgn[128];
  float cnt = (float)(b - a);
  hgn[t] = ((s0 + s1) + (s2 + s3)) / fmaxf(cnt, 1.f);
  __syncthreads();
  if (t < 64) {
    float r = br1[t];
#pragma unroll 8
    for (int k = 0; k < 128; k++) r = fmaf(hgn[k], Wr1[k * 64 + t], r);
    r = fmaxf(r, 0.f);
    float p = r * Wr2[t];
#pragma unroll
    for (int k = 1; k < 64; k <<= 1) p += __shfl_xor(p, k);
    if (t == 0) out[g] = p + br2[0];
  }
}

extern "C" void kernel_launch(void* const* d_in, const int* in_sizes, int n_in,
                              void* d_out, int out_size, void* d_ws, size_t ws_size,
                              hipStream_t stream) {
  (void)in_sizes; (void)n_in; (void)out_size; (void)ws_size;
  const float* x     = (const float*)d_in[0];
  const float* W1s   = (const float*)d_in[1];
  const float* b1s   = (const float*)d_in[2];
  const float* W1d   = (const float*)d_in[3];
  const float* b1d   = (const float*)d_in[4];
  const float* attn1 = (const float*)d_in[5];
  const float* W2s   = (const float*)d_in[6];
  const float* b2s   = (const float*)d_in[7];
  const float* W2d   = (const float*)d_in[8];
  const float* b2d   = (const float*)d_in[9];
  const float* attn2 = (const float*)d_in[10];
  const float* Wr1   = (const float*)d_in[11];
  const float* br1   = (const float*)d_in[12];
  const float* Wr2   = (const float*)d_in[13];
  const float* br2   = (const float*)d_in[14];
  const int* src     = (const int*)d_in[15];
  const int* dst     = (const int*)d_in[16];
  const int* gid     = (const int*)d_in[17];
  float* out = (float*)d_out;

  char* ws = (char*)d_ws;
  float* hs1     = (float*)(ws + 0);          // N*512 f32
  float* hd1     = (float*)(ws + 20480000);   // N*512 f32
  float* h1      = (float*)(ws + 40960000);   // N*512 f32
  int*   srcl    = (int*)(ws + 61440000);     // E int
  int*   row_off = (int*)(ws + 62720000);     // (N+1) int
  int*   cnt     = (int*)(ws + 62760448);     // N int
  int*   fill    = (int*)(ws + 62800448);     // N int
  float* hs2 = hs1;
  float* hd2 = hd1;
  float* h2  = h1;

  hipMemsetAsync(cnt, 0, 2 * N_NODES * 4, stream);

  hist_kernel<<<N_EDGES / 256, 256, 0, stream>>>(dst, cnt);
  scan_kernel<<<1, 1024, 0, stream>>>(cnt, row_off);
  scatter_kernel<<<N_EDGES / 256, 256, 0, stream>>>(src, dst, row_off, fill, srcl);

  dual_gemm<DIM_IN, HD, 128><<<dim3(HD / 64, (N_NODES + 127) / 128), 256, 0, stream>>>(
      x, W1s, b1s, W1d, b1d, hs1, hd1, N_NODES);
  fused_gat1<<<(2 * N_NODES + 3) / 4, 256, 0, stream>>>(hs1, hd1, attn1, row_off, srcl, h1);

  dual_gemm<HD, DD, 32><<<dim3(DD / 64, (N_NODES + 31) / 32), 256, 0, stream>>>(
      h1, W2s, b2s, W2d, b2d, hs2, hd2, N_NODES);
  fused_gat2<<<(N_NODES + 3) / 4, 256, 0, stream>>>(hs2, hd2, attn2, row_off, srcl, h2);

  final_kernel<<<GG, 128, 0, stream>>>(h2, gid, Wr1, br1, Wr2, br2, out);
}

// Round 9
// 249.213 us; speedup vs baseline: 1.2689x; 1.1844x over previous
//
#include <hip/hip_runtime.h>

typedef __attribute__((ext_vector_type(8))) short bf16x8;
typedef __attribute__((ext_vector_type(4))) float f32x4;

#define N_NODES 10000
#define N_EDGES 320000
#define DIM_IN  256
#define DD      128
#define HH      4
#define HD      512
#define GG      64

// ---------------- CSR build ----------------
__global__ void hist_kernel(const int* __restrict__ dst, int* __restrict__ cnt) {
  int e = blockIdx.x * 256 + threadIdx.x;
  atomicAdd(&cnt[dst[e]], 1);
}

__global__ void scan_kernel(const int* __restrict__ cnt, int* __restrict__ row_off) {
  __shared__ int part[1024];
  int t = threadIdx.x;
  int base = t * 10;
  int s = 0;
#pragma unroll
  for (int i = 0; i < 10; i++) { int idx = base + i; if (idx < N_NODES) s += cnt[idx]; }
  part[t] = s;
  __syncthreads();
  for (int off = 1; off < 1024; off <<= 1) {
    int v = (t >= off) ? part[t - off] : 0;
    __syncthreads();
    part[t] += v;
    __syncthreads();
  }
  int run = part[t] - s;
  for (int i = 0; i < 10; i++) {
    int idx = base + i;
    if (idx < N_NODES) { row_off[idx] = run; run += cnt[idx]; }
  }
  if (t == 1023) row_off[N_NODES] = part[1023];
}

__global__ void scatter_kernel(const int* __restrict__ src, const int* __restrict__ dst,
                               const int* __restrict__ row_off,
                               int* __restrict__ fill, int* __restrict__ srcl) {
  int e = blockIdx.x * 256 + threadIdx.x;
  int d = dst[e];
  int pos = row_off[d] + atomicAdd(&fill[d], 1);
  srcl[pos] = src[e];
}

// ---------------- split-precision helpers ----------------
__device__ inline void split4(float4 v, ushort4& h, ushort4& l) {
  uint bx = __float_as_uint(v.x), by = __float_as_uint(v.y);
  uint bz = __float_as_uint(v.z), bw = __float_as_uint(v.w);
  float rx = v.x - __uint_as_float(bx & 0xFFFF0000u);
  float ry = v.y - __uint_as_float(by & 0xFFFF0000u);
  float rz = v.z - __uint_as_float(bz & 0xFFFF0000u);
  float rw = v.w - __uint_as_float(bw & 0xFFFF0000u);
  h.x = (unsigned short)(bx >> 16); h.y = (unsigned short)(by >> 16);
  h.z = (unsigned short)(bz >> 16); h.w = (unsigned short)(bw >> 16);
  l.x = (unsigned short)(__float_as_uint(rx) >> 16);
  l.y = (unsigned short)(__float_as_uint(ry) >> 16);
  l.z = (unsigned short)(__float_as_uint(rz) >> 16);
  l.w = (unsigned short)(__float_as_uint(rw) >> 16);
}

// row-major fp32 [M][K] -> bf16 hi/lo [M][K]
__global__ __launch_bounds__(256) void split_rm(const float* __restrict__ in,
                                                ushort* __restrict__ oh,
                                                ushort* __restrict__ ol, int n4) {
  int i = blockIdx.x * 256 + threadIdx.x;
  if (i >= n4) return;
  float4 v = ((const float4*)in)[i];
  ushort4 h, l;
  split4(v, h, l);
  ((ushort4*)oh)[i] = h;
  ((ushort4*)ol)[i] = l;
}

// fp32 [K][N] -> bf16 hi/lo transposed [N][K]
__global__ __launch_bounds__(256) void split_tr(const float* __restrict__ in,
                                                ushort* __restrict__ oh,
                                                ushort* __restrict__ ol,
                                                int K, int N, int lgN) {
  int id = blockIdx.x * 256 + threadIdx.x;
  int n = id & (N - 1);
  int kq = id >> lgN;
  if (kq >= (K >> 2)) return;
  int k = kq * 4;
  float4 v;
  v.x = in[(size_t)(k + 0) * N + n];
  v.y = in[(size_t)(k + 1) * N + n];
  v.z = in[(size_t)(k + 2) * N + n];
  v.w = in[(size_t)(k + 3) * N + n];
  ushort4 h, l;
  split4(v, h, l);
  *(ushort4*)(oh + (size_t)n * K + k) = h;
  *(ushort4*)(ol + (size_t)n * K + k) = l;
}

// ---------------- dual GEMM via bf16x3 MFMA ----------------
// A: bf16 hi/lo [M][K] k-major. B: bf16 hi/lo [NCOL][K] (transposed, k-major).
// C1 = A@B1^T + bias1, C2 = A@B2^T + bias2 (i.e. original B [K][NCOL]).
// Block: 256 thr = 4 waves (2x2), tile 64x64, BK=32.
template <int K, int NCOL>
__global__ __launch_bounds__(256) void dual_gemm_mfma(
    const ushort* __restrict__ Ahg, const ushort* __restrict__ Alg,
    const ushort* __restrict__ B1hg, const ushort* __restrict__ B1lg,
    const float* __restrict__ bias1,
    const ushort* __restrict__ B2hg, const ushort* __restrict__ B2lg,
    const float* __restrict__ bias2,
    float* __restrict__ C1, float* __restrict__ C2, int M) {
  __shared__ ushort Ah[64][40], Al[64][40];
  __shared__ ushort B1h[64][40], B1l[64][40], B2h[64][40], B2l[64][40];
  int t = threadIdx.x;
  int lane = t & 63, wv = t >> 6;
  int wr = wv >> 1, wc = wv & 1;
  int l15 = lane & 15, l16 = lane >> 4;
  int col0 = blockIdx.x * 64, m0 = blockIdx.y * 64;

  int sr = t >> 2;           // staging row (A) / col (B): 0..63
  int sk = (t & 3) * 8;      // staging k offset: 0,8,16,24
  bool arow_ok = (m0 + sr) < M;
  const ushort* pAh = Ahg + (size_t)(m0 + sr) * K + sk;
  const ushort* pAl = Alg + (size_t)(m0 + sr) * K + sk;
  const ushort* pB1h = B1hg + (size_t)(col0 + sr) * K + sk;
  const ushort* pB1l = B1lg + (size_t)(col0 + sr) * K + sk;
  const ushort* pB2h = B2hg + (size_t)(col0 + sr) * K + sk;
  const ushort* pB2l = B2lg + (size_t)(col0 + sr) * K + sk;

  f32x4 zero = {0.f, 0.f, 0.f, 0.f};
  f32x4 acc1[2][2], acc2[2][2];
#pragma unroll
  for (int i = 0; i < 2; i++)
#pragma unroll
    for (int j = 0; j < 2; j++) { acc1[i][j] = zero; acc2[i][j] = zero; }

  for (int k0 = 0; k0 < K; k0 += 32) {
    uint4 vah = arow_ok ? *(const uint4*)(pAh + k0) : make_uint4(0u, 0u, 0u, 0u);
    uint4 val = arow_ok ? *(const uint4*)(pAl + k0) : make_uint4(0u, 0u, 0u, 0u);
    uint4 v1h = *(const uint4*)(pB1h + k0);
    uint4 v1l = *(const uint4*)(pB1l + k0);
    uint4 v2h = *(const uint4*)(pB2h + k0);
    uint4 v2l = *(const uint4*)(pB2l + k0);
    __syncthreads();
    *(uint4*)&Ah[sr][sk] = vah;
    *(uint4*)&Al[sr][sk] = val;
    *(uint4*)&B1h[sr][sk] = v1h;
    *(uint4*)&B1l[sr][sk] = v1l;
    *(uint4*)&B2h[sr][sk] = v2h;
    *(uint4*)&B2l[sr][sk] = v2l;
    __syncthreads();
#pragma unroll
    for (int cb = 0; cb < 2; cb++) {
      int bc = wc * 32 + cb * 16 + l15;
      bf16x8 b1hf = *(const bf16x8*)&B1h[bc][l16 * 8];
      bf16x8 b1lf = *(const bf16x8*)&B1l[bc][l16 * 8];
      bf16x8 b2hf = *(const bf16x8*)&B2h[bc][l16 * 8];
      bf16x8 b2lf = *(const bf16x8*)&B2l[bc][l16 * 8];
#pragma unroll
      for (int rb = 0; rb < 2; rb++) {
        int arw = wr * 32 + rb * 16 + l15;
        bf16x8 ahf = *(const bf16x8*)&Ah[arw][l16 * 8];
        bf16x8 alf = *(const bf16x8*)&Al[arw][l16 * 8];
        acc1[rb][cb] = __builtin_amdgcn_mfma_f32_16x16x32_bf16(ahf, b1hf, acc1[rb][cb], 0, 0, 0);
        acc1[rb][cb] = __builtin_amdgcn_mfma_f32_16x16x32_bf16(ahf, b1lf, acc1[rb][cb], 0, 0, 0);
        acc1[rb][cb] = __builtin_amdgcn_mfma_f32_16x16x32_bf16(alf, b1hf, acc1[rb][cb], 0, 0, 0);
        acc2[rb][cb] = __builtin_amdgcn_mfma_f32_16x16x32_bf16(ahf, b2hf, acc2[rb][cb], 0, 0, 0);
        acc2[rb][cb] = __builtin_amdgcn_mfma_f32_16x16x32_bf16(ahf, b2lf, acc2[rb][cb], 0, 0, 0);
        acc2[rb][cb] = __builtin_amdgcn_mfma_f32_16x16x32_bf16(alf, b2hf, acc2[rb][cb], 0, 0, 0);
      }
    }
  }
#pragma unroll
  for (int rb = 0; rb < 2; rb++) {
#pragma unroll
    for (int cb = 0; cb < 2; cb++) {
      int row = m0 + wr * 32 + rb * 16 + l16 * 4;
      int col = col0 + wc * 32 + cb * 16 + l15;
      float bb1 = bias1[col], bb2 = bias2[col];
#pragma unroll
      for (int rr = 0; rr < 4; rr++) {
        if (row + rr < M) {
          C1[(size_t)(row + rr) * NCOL + col] = acc1[rb][cb][rr] + bb1;
          C2[(size_t)(row + rr) * NCOL + col] = acc2[rb][cb][rr] + bb2;
        }
      }
    }
  }
}

// ---------------- layer 1 fused: wave per (node, head-half) --------------------
__global__ __launch_bounds__(256) void fused_gat1(
    const float* __restrict__ hs, const float* __restrict__ hd,
    const float* __restrict__ attn, const int* __restrict__ row_off,
    const int* __restrict__ srcl, float* __restrict__ out) {
  int t = threadIdx.x;
  int w = t >> 6, lane = t & 63;
  int W = blockIdx.x * 4 + w;           // 0..19999
  int half = (W >= N_NODES) ? 1 : 0;
  int v = W - half * N_NODES;
  int off = half * 256 + lane * 4;
  int start = row_off[v];
  int deg = row_off[v + 1] - start;

  float4 a = *(const float4*)(attn + off);
  float4 hdv = *(const float4*)(hd + (size_t)v * HD + off);
  const float* hsl = hs + off;

  float ssum = 0.f;
  float4 acc = make_float4(0.f, 0.f, 0.f, 0.f);

  for (int base = 0; base < deg; base += 64) {
    int nc = deg - base; nc = nc < 64 ? nc : 64;
    int myidx = (lane < nc) ? srcl[start + base + lane] : 0;

    float4 c0 = {0,0,0,0}, c1 = {0,0,0,0}, c2 = {0,0,0,0}, c3 = {0,0,0,0};
    if (0 < nc) c0 = *(const float4*)(hsl + (size_t)__builtin_amdgcn_readlane(myidx, 0) * HD);
    if (1 < nc) c1 = *(const float4*)(hsl + (size_t)__builtin_amdgcn_readlane(myidx, 1) * HD);
    if (2 < nc) c2 = *(const float4*)(hsl + (size_t)__builtin_amdgcn_readlane(myidx, 2) * HD);
    if (3 < nc) c3 = *(const float4*)(hsl + (size_t)__builtin_amdgcn_readlane(myidx, 3) * HD);

    for (int i0 = 0; i0 < nc; i0 += 4) {
#define GAT1_STEP(Q, C)                                                               \
      if (i0 + Q < nc) {                                                              \
        float4 u = C;                                                                 \
        int nx = i0 + 4 + Q;                                                          \
        if (nx < nc)                                                                  \
          C = *(const float4*)(hsl + (size_t)__builtin_amdgcn_readlane(myidx, nx) * HD); \
        float e0 = u.x + hdv.x; e0 = fmaxf(e0, 0.2f * e0);                            \
        float e1 = u.y + hdv.y; e1 = fmaxf(e1, 0.2f * e1);                            \
        float e2 = u.z + hdv.z; e2 = fmaxf(e2, 0.2f * e2);                            \
        float e3 = u.w + hdv.w; e3 = fmaxf(e3, 0.2f * e3);                            \
        float part = fmaf(e0, a.x, fmaf(e1, a.y, fmaf(e2, a.z, e3 * a.w)));           \
        _Pragma("unroll")                                                             \
        for (int k = 1; k < 32; k <<= 1) part += __shfl_xor(part, k);                 \
        float wg = __expf(part);                                                      \
        ssum += wg;                                                                   \
        acc.x = fmaf(wg, u.x, acc.x);                                                 \
        acc.y = fmaf(wg, u.y, acc.y);                                                 \
        acc.z = fmaf(wg, u.z, acc.z);                                                 \
        acc.w = fmaf(wg, u.w, acc.w);                                                 \
      }
      GAT1_STEP(0, c0)
      GAT1_STEP(1, c1)
      GAT1_STEP(2, c2)
      GAT1_STEP(3, c3)
#undef GAT1_STEP
    }
  }
  float inv = ssum > 0.f ? 1.f / ssum : 0.f;
  *(float4*)(out + (size_t)v * HD + off) =
      make_float4(acc.x * inv, acc.y * inv, acc.z * inv, acc.w * inv);
}

// ---------------- layer 2 fused: wave per node, 4 x 16-lane groups, 2-deep -----
__global__ __launch_bounds__(256) void fused_gat2(
    const float* __restrict__ hs, const float* __restrict__ hd,
    const float* __restrict__ attn, const int* __restrict__ row_off,
    const int* __restrict__ srcl, float* __restrict__ out) {
  int t = threadIdx.x;
  int w = t >> 6, lane = t & 63, grp = lane >> 4, sl = lane & 15;
  int v = blockIdx.x * 4 + w;
  int start = row_off[v];
  int deg = row_off[v + 1] - start;

  const float* ap = attn + sl * 8;
  const float* hp = hd + (size_t)v * DD + sl * 8;
  float4 a0 = *(const float4*)ap, a1 = *(const float4*)(ap + 4);
  float4 g0 = *(const float4*)hp, g1 = *(const float4*)(hp + 4);
  float areg[8] = {a0.x, a0.y, a0.z, a0.w, a1.x, a1.y, a1.z, a1.w};
  float hdreg[8] = {g0.x, g0.y, g0.z, g0.w, g1.x, g1.y, g1.z, g1.w};
  const float* hsl = hs + sl * 8;

  float ssum = 0.f;
  float acc[8] = {0.f, 0.f, 0.f, 0.f, 0.f, 0.f, 0.f, 0.f};

  float4 c0a = {0,0,0,0}, c0b = {0,0,0,0}, c1a = {0,0,0,0}, c1b = {0,0,0,0};
  if (grp < deg) { const float* p = hsl + (size_t)srcl[start + grp] * DD; c0a = *(const float4*)p; c0b = *(const float4*)(p + 4); }
  if (grp + 4 < deg) { const float* p = hsl + (size_t)srcl[start + grp + 4] * DD; c1a = *(const float4*)p; c1b = *(const float4*)(p + 4); }

  for (int i = grp; i < deg; i += 8) {
    float u0[8] = {c0a.x, c0a.y, c0a.z, c0a.w, c0b.x, c0b.y, c0b.z, c0b.w};
    float u1[8] = {c1a.x, c1a.y, c1a.z, c1a.w, c1b.x, c1b.y, c1b.z, c1b.w};
    bool have1 = (i + 4) < deg;
    if (i + 8 < deg) { const float* p = hsl + (size_t)srcl[start + i + 8] * DD; c0a = *(const float4*)p; c0b = *(const float4*)(p + 4); }
    if (i + 12 < deg) { const float* p = hsl + (size_t)srcl[start + i + 12] * DD; c1a = *(const float4*)p; c1b = *(const float4*)(p + 4); }
    float part0 = 0.f, part1 = 0.f;
#pragma unroll
    for (int j = 0; j < 8; j++) {
      float e0 = u0[j] + hdreg[j]; e0 = fmaxf(e0, 0.2f * e0);
      part0 = fmaf(e0, areg[j], part0);
      float e1 = u1[j] + hdreg[j]; e1 = fmaxf(e1, 0.2f * e1);
      part1 = fmaf(e1, areg[j], part1);
    }
#pragma unroll
    for (int k = 1; k < 16; k <<= 1) {
      part0 += __shfl_xor(part0, k);
      part1 += __shfl_xor(part1, k);
    }
    float wg0 = __expf(part0);
    float wg1 = have1 ? __expf(part1) : 0.f;
    ssum += wg0 + wg1;
#pragma unroll
    for (int j = 0; j < 8; j++)
      acc[j] = fmaf(wg0, u0[j], fmaf(wg1, u1[j], acc[j]));
  }
#pragma unroll
  for (int j = 0; j < 8; j++) {
    acc[j] += __shfl_xor(acc[j], 16);
    acc[j] += __shfl_xor(acc[j], 32);
  }
  ssum += __shfl_xor(ssum, 16);
  ssum += __shfl_xor(ssum, 32);
  float inv = ssum > 0.f ? 1.f / ssum : 0.f;
  if (lane < 16) {
    float* op = out + (size_t)v * DD + sl * 8;
    *(float4*)op = make_float4(acc[0] * inv, acc[1] * inv, acc[2] * inv, acc[3] * inv);
    *(float4*)(op + 4) = make_float4(acc[4] * inv, acc[5] * inv, acc[6] * inv, acc[7] * inv);
  }
}

// ---------------- pooling (binary search on sorted gid) + readout MLP ----------
__global__ __launch_bounds__(128) void final_kernel(
    const float* __restrict__ h2, const int* __restrict__ gid,
    const float* __restrict__ Wr1, const float* __restrict__ br1,
    const float* __restrict__ Wr2, const float* __restrict__ br2,
    float* __restrict__ out) {
  int g = blockIdx.x, t = threadIdx.x;
  int a, b;
  { int l = 0, h = N_NODES; while (l < h) { int m = (l + h) >> 1; if (gid[m] < g) l = m + 1; else h = m; } a = l; }
  { int l = a, h = N_NODES; while (l < h) { int m = (l + h) >> 1; if (gid[m] < g + 1) l = m + 1; else h = m; } b = l; }
  float s0 = 0.f, s1 = 0.f, s2 = 0.f, s3 = 0.f;
  int v = a;
  for (; v + 3 < b; v += 4) {
    s0 += h2[(size_t)(v + 0) * DD + t];
    s1 += h2[(size_t)(v + 1) * DD + t];
    s2 += h2[(size_t)(v + 2) * DD + t];
    s3 += h2[(size_t)(v + 3) * DD + t];
  }
  for (; v < b; v++) s0 += h2[(size_t)v * DD + t];
  __shared__ float hgn[128];
  float cnt = (float)(b - a);
  hgn[t] = ((s0 + s1) + (s2 + s3)) / fmaxf(cnt, 1.f);
  __syncthreads();
  if (t < 64) {
    float r = br1[t];
#pragma unroll 8
    for (int k = 0; k < 128; k++) r = fmaf(hgn[k], Wr1[k * 64 + t], r);
    r = fmaxf(r, 0.f);
    float p = r * Wr2[t];
#pragma unroll
    for (int k = 1; k < 64; k <<= 1) p += __shfl_xor(p, k);
    if (t == 0) out[g] = p + br2[0];
  }
}

extern "C" void kernel_launch(void* const* d_in, const int* in_sizes, int n_in,
                              void* d_out, int out_size, void* d_ws, size_t ws_size,
                              hipStream_t stream) {
  (void)in_sizes; (void)n_in; (void)out_size; (void)ws_size;
  const float* x     = (const float*)d_in[0];
  const float* W1s   = (const float*)d_in[1];
  const float* b1s   = (const float*)d_in[2];
  const float* W1d   = (const float*)d_in[3];
  const float* b1d   = (const float*)d_in[4];
  const float* attn1 = (const float*)d_in[5];
  const float* W2s   = (const float*)d_in[6];
  const float* b2s   = (const float*)d_in[7];
  const float* W2d   = (const float*)d_in[8];
  const float* b2d   = (const float*)d_in[9];
  const float* attn2 = (const float*)d_in[10];
  const float* Wr1   = (const float*)d_in[11];
  const float* br1   = (const float*)d_in[12];
  const float* Wr2   = (const float*)d_in[13];
  const float* br2   = (const float*)d_in[14];
  const int* src     = (const int*)d_in[15];
  const int* dst     = (const int*)d_in[16];
  const int* gid     = (const int*)d_in[17];
  float* out = (float*)d_out;

  char* ws = (char*)d_ws;
  float*  hs1     = (float*)(ws + 0);           // [10000][512] f32 (20.48 MB)
  float*  hd1     = (float*)(ws + 20480000);    // [10000][512] f32
  float*  h1      = (float*)(ws + 40960000);    // [10000][512] f32; later h2
  ushort* xh      = (ushort*)(ws + 61440000);   // [10000][256] bf16 (5.12 MB)
  ushort* xl      = (ushort*)(ws + 66560000);   // 5.12 MB
  int*    srcl    = (int*)(ws + 71680000);      // E int (1.28 MB)
  int*    row_off = (int*)(ws + 72960000);      // N+1
  int*    cnt     = (int*)(ws + 73000064);      // N
  int*    fill    = (int*)(ws + 73040064);      // N
  ushort* b1sh    = (ushort*)(ws + 73080064);   // [512][256] bf16 (0.26 MB)
  ushort* b1sl    = (ushort*)(ws + 73342208);
  ushort* b1dh    = (ushort*)(ws + 73604352);
  ushort* b1dl    = (ushort*)(ws + 73866496);
  ushort* b2sh    = (ushort*)(ws + 74128640);   // [128][512] bf16 (0.13 MB)
  ushort* b2sl    = (ushort*)(ws + 74259712);
  ushort* b2dh    = (ushort*)(ws + 74390784);
  ushort* b2dl    = (ushort*)(ws + 74521856);
  // reuse after gat1:
  ushort* h1h     = (ushort*)(ws + 20480000);   // [10000][512] bf16 (10.24 MB)
  ushort* h1l     = (ushort*)(ws + 30720000);
  float*  hs2     = (float*)(ws + 0);           // [10000][128] f32 (5.12 MB)
  float*  hd2     = (float*)(ws + 5120000);
  float*  h2      = h1;

  hipMemsetAsync(cnt, 0, 2 * N_NODES * 4, stream);

  hist_kernel<<<N_EDGES / 256, 256, 0, stream>>>(dst, cnt);
  scan_kernel<<<1, 1024, 0, stream>>>(cnt, row_off);
  scatter_kernel<<<N_EDGES / 256, 256, 0, stream>>>(src, dst, row_off, fill, srcl);

  // preconvert: x and layer-1 weights
  split_rm<<<(N_NODES * DIM_IN / 4 + 255) / 256, 256, 0, stream>>>(x, xh, xl, N_NODES * DIM_IN / 4);
  split_tr<<<(HD * (DIM_IN / 4) + 255) / 256, 256, 0, stream>>>(W1s, b1sh, b1sl, DIM_IN, HD, 9);
  split_tr<<<(HD * (DIM_IN / 4) + 255) / 256, 256, 0, stream>>>(W1d, b1dh, b1dl, DIM_IN, HD, 9);
  split_tr<<<(DD * (HD / 4) + 255) / 256, 256, 0, stream>>>(W2s, b2sh, b2sl, HD, DD, 7);
  split_tr<<<(DD * (HD / 4) + 255) / 256, 256, 0, stream>>>(W2d, b2dh, b2dl, HD, DD, 7);

  dual_gemm_mfma<DIM_IN, HD><<<dim3(HD / 64, (N_NODES + 63) / 64), 256, 0, stream>>>(
      xh, xl, b1sh, b1sl, b1s, b1dh, b1dl, b1d, hs1, hd1, N_NODES);
  fused_gat1<<<(2 * N_NODES + 3) / 4, 256, 0, stream>>>(hs1, hd1, attn1, row_off, srcl, h1);

  split_rm<<<(N_NODES * HD / 4 + 255) / 256, 256, 0, stream>>>(h1, h1h, h1l, N_NODES * HD / 4);
  dual_gemm_mfma<HD, DD><<<dim3(DD / 64, (N_NODES + 63) / 64), 256, 0, stream>>>(
      h1h, h1l, b2sh, b2sl, b2s, b2dh, b2dl, b2d, hs2, hd2, N_NODES);
  fused_gat2<<<(N_NODES + 3) / 4, 256, 0, stream>>>(hs2, hd2, attn2, row_off, srcl, h2);

  final_kernel<<<GG, 128, 0, stream>>>(h2, gid, Wr1, br1, Wr2, br2, out);
}

// Round 10
// 248.897 us; speedup vs baseline: 1.2705x; 1.0013x over previous
//
#include <hip/hip_runtime.h>

typedef __attribute__((ext_vector_type(8))) short bf16x8;
typedef __attribute__((ext_vector_type(4))) float f32x4;

#define N_NODES 10000
#define N_EDGES 320000
#define DIM_IN  256
#define DD      128
#define HH      4
#define HD      512
#define GG      64

// ---------------- CSR build ----------------
__global__ void hist_kernel(const int* __restrict__ dst, int* __restrict__ cnt) {
  int e = blockIdx.x * 256 + threadIdx.x;
  atomicAdd(&cnt[dst[e]], 1);
}

__global__ void scan_kernel(const int* __restrict__ cnt, int* __restrict__ row_off) {
  __shared__ int part[1024];
  int t = threadIdx.x;
  int base = t * 10;
  int s = 0;
#pragma unroll
  for (int i = 0; i < 10; i++) { int idx = base + i; if (idx < N_NODES) s += cnt[idx]; }
  part[t] = s;
  __syncthreads();
  for (int off = 1; off < 1024; off <<= 1) {
    int v = (t >= off) ? part[t - off] : 0;
    __syncthreads();
    part[t] += v;
    __syncthreads();
  }
  int run = part[t] - s;
  for (int i = 0; i < 10; i++) {
    int idx = base + i;
    if (idx < N_NODES) { row_off[idx] = run; run += cnt[idx]; }
  }
  if (t == 1023) row_off[N_NODES] = part[1023];
}

__global__ void scatter_kernel(const int* __restrict__ src, const int* __restrict__ dst,
                               const int* __restrict__ row_off,
                               int* __restrict__ fill, int* __restrict__ srcl) {
  int e = blockIdx.x * 256 + threadIdx.x;
  int d = dst[e];
  int pos = row_off[d] + atomicAdd(&fill[d], 1);
  srcl[pos] = src[e];
}

// ---------------- split-precision helpers ----------------
__device__ inline void split4(float4 v, ushort4& h, ushort4& l) {
  uint bx = __float_as_uint(v.x), by = __float_as_uint(v.y);
  uint bz = __float_as_uint(v.z), bw = __float_as_uint(v.w);
  float rx = v.x - __uint_as_float(bx & 0xFFFF0000u);
  float ry = v.y - __uint_as_float(by & 0xFFFF0000u);
  float rz = v.z - __uint_as_float(bz & 0xFFFF0000u);
  float rw = v.w - __uint_as_float(bw & 0xFFFF0000u);
  h.x = (unsigned short)(bx >> 16); h.y = (unsigned short)(by >> 16);
  h.z = (unsigned short)(bz >> 16); h.w = (unsigned short)(bw >> 16);
  l.x = (unsigned short)(__float_as_uint(rx) >> 16);
  l.y = (unsigned short)(__float_as_uint(ry) >> 16);
  l.z = (unsigned short)(__float_as_uint(rz) >> 16);
  l.w = (unsigned short)(__float_as_uint(rw) >> 16);
}

// row-major fp32 [M][K] -> bf16 hi/lo [M][K]
__global__ __launch_bounds__(256) void split_rm(const float* __restrict__ in,
                                                ushort* __restrict__ oh,
                                                ushort* __restrict__ ol, int n4) {
  int i = blockIdx.x * 256 + threadIdx.x;
  if (i >= n4) return;
  float4 v = ((const float4*)in)[i];
  ushort4 h, l;
  split4(v, h, l);
  ((ushort4*)oh)[i] = h;
  ((ushort4*)ol)[i] = l;
}

// two fp32 [K][N] -> bf16 hi/lo transposed [N][K]; blockIdx.y selects matrix
__global__ __launch_bounds__(256) void split_tr2(
    const float* __restrict__ in0, ushort* __restrict__ oh0, ushort* __restrict__ ol0,
    const float* __restrict__ in1, ushort* __restrict__ oh1, ushort* __restrict__ ol1,
    int K, int N, int lgN) {
  const float* in = blockIdx.y ? in1 : in0;
  ushort* oh = blockIdx.y ? oh1 : oh0;
  ushort* ol = blockIdx.y ? ol1 : ol0;
  int id = blockIdx.x * 256 + threadIdx.x;
  int n = id & (N - 1);
  int kq = id >> lgN;
  if (kq >= (K >> 2)) return;
  int k = kq * 4;
  float4 v;
  v.x = in[(size_t)(k + 0) * N + n];
  v.y = in[(size_t)(k + 1) * N + n];
  v.z = in[(size_t)(k + 2) * N + n];
  v.w = in[(size_t)(k + 3) * N + n];
  ushort4 h, l;
  split4(v, h, l);
  *(ushort4*)(oh + (size_t)n * K + k) = h;
  *(ushort4*)(ol + (size_t)n * K + k) = l;
}

// ---------------- dual GEMM via bf16x3 MFMA (register-prefetch pipelined) ------
template <int K, int NCOL>
__global__ __launch_bounds__(256) void dual_gemm_mfma(
    const ushort* __restrict__ Ahg, const ushort* __restrict__ Alg,
    const ushort* __restrict__ B1hg, const ushort* __restrict__ B1lg,
    const float* __restrict__ bias1,
    const ushort* __restrict__ B2hg, const ushort* __restrict__ B2lg,
    const float* __restrict__ bias2,
    float* __restrict__ C1, float* __restrict__ C2, int M) {
  __shared__ ushort Ah[64][40], Al[64][40];
  __shared__ ushort B1h[64][40], B1l[64][40], B2h[64][40], B2l[64][40];
  int t = threadIdx.x;
  int lane = t & 63, wv = t >> 6;
  int wr = wv >> 1, wc = wv & 1;
  int l15 = lane & 15, l16 = lane >> 4;
  int col0 = blockIdx.x * 64, m0 = blockIdx.y * 64;

  int sr = t >> 2;           // staging row (A) / col (B): 0..63
  int sk = (t & 3) * 8;      // staging k offset: 0,8,16,24
  bool arow_ok = (m0 + sr) < M;
  const ushort* pAh = Ahg + (size_t)(m0 + sr) * K + sk;
  const ushort* pAl = Alg + (size_t)(m0 + sr) * K + sk;
  const ushort* pB1h = B1hg + (size_t)(col0 + sr) * K + sk;
  const ushort* pB1l = B1lg + (size_t)(col0 + sr) * K + sk;
  const ushort* pB2h = B2hg + (size_t)(col0 + sr) * K + sk;
  const ushort* pB2l = B2lg + (size_t)(col0 + sr) * K + sk;

  f32x4 zero = {0.f, 0.f, 0.f, 0.f};
  f32x4 acc1[2][2], acc2[2][2];
#pragma unroll
  for (int i = 0; i < 2; i++)
#pragma unroll
    for (int j = 0; j < 2; j++) { acc1[i][j] = zero; acc2[i][j] = zero; }

  uint4 vah, val, v1h, v1l, v2h, v2l;
#define LOADK(KO)                                                            \
  vah = arow_ok ? *(const uint4*)(pAh + (KO)) : make_uint4(0u, 0u, 0u, 0u);  \
  val = arow_ok ? *(const uint4*)(pAl + (KO)) : make_uint4(0u, 0u, 0u, 0u);  \
  v1h = *(const uint4*)(pB1h + (KO));                                        \
  v1l = *(const uint4*)(pB1l + (KO));                                        \
  v2h = *(const uint4*)(pB2h + (KO));                                        \
  v2l = *(const uint4*)(pB2l + (KO));
  LOADK(0)
  for (int k0 = 0; k0 < K; k0 += 32) {
    __syncthreads();
    *(uint4*)&Ah[sr][sk] = vah;
    *(uint4*)&Al[sr][sk] = val;
    *(uint4*)&B1h[sr][sk] = v1h;
    *(uint4*)&B1l[sr][sk] = v1l;
    *(uint4*)&B2h[sr][sk] = v2h;
    *(uint4*)&B2l[sr][sk] = v2l;
    __syncthreads();
    if (k0 + 32 < K) { LOADK(k0 + 32) }   // issue next-tile loads before MFMA
#pragma unroll
    for (int cb = 0; cb < 2; cb++) {
      int bc = wc * 32 + cb * 16 + l15;
      bf16x8 b1hf = *(const bf16x8*)&B1h[bc][l16 * 8];
      bf16x8 b1lf = *(const bf16x8*)&B1l[bc][l16 * 8];
      bf16x8 b2hf = *(const bf16x8*)&B2h[bc][l16 * 8];
      bf16x8 b2lf = *(const bf16x8*)&B2l[bc][l16 * 8];
#pragma unroll
      for (int rb = 0; rb < 2; rb++) {
        int arw = wr * 32 + rb * 16 + l15;
        bf16x8 ahf = *(const bf16x8*)&Ah[arw][l16 * 8];
        bf16x8 alf = *(const bf16x8*)&Al[arw][l16 * 8];
        acc1[rb][cb] = __builtin_amdgcn_mfma_f32_16x16x32_bf16(ahf, b1hf, acc1[rb][cb], 0, 0, 0);
        acc1[rb][cb] = __builtin_amdgcn_mfma_f32_16x16x32_bf16(ahf, b1lf, acc1[rb][cb], 0, 0, 0);
        acc1[rb][cb] = __builtin_amdgcn_mfma_f32_16x16x32_bf16(alf, b1hf, acc1[rb][cb], 0, 0, 0);
        acc2[rb][cb] = __builtin_amdgcn_mfma_f32_16x16x32_bf16(ahf, b2hf, acc2[rb][cb], 0, 0, 0);
        acc2[rb][cb] = __builtin_amdgcn_mfma_f32_16x16x32_bf16(ahf, b2lf, acc2[rb][cb], 0, 0, 0);
        acc2[rb][cb] = __builtin_amdgcn_mfma_f32_16x16x32_bf16(alf, b2hf, acc2[rb][cb], 0, 0, 0);
      }
    }
  }
#undef LOADK
#pragma unroll
  for (int rb = 0; rb < 2; rb++) {
#pragma unroll
    for (int cb = 0; cb < 2; cb++) {
      int row = m0 + wr * 32 + rb * 16 + l16 * 4;
      int col = col0 + wc * 32 + cb * 16 + l15;
      float bb1 = bias1[col], bb2 = bias2[col];
#pragma unroll
      for (int rr = 0; rr < 4; rr++) {
        if (row + rr < M) {
          C1[(size_t)(row + rr) * NCOL + col] = acc1[rb][cb][rr] + bb1;
          C2[(size_t)(row + rr) * NCOL + col] = acc2[rb][cb][rr] + bb2;
        }
      }
    }
  }
}

// ---------------- layer 1 fused: wave per (node, head-slice), XCD-pinned -------
// 40000 wave-items as 10000 blocks x 4 waves. Block b: slice = b & 3 (one head,
// 128 floats); nodes 4*(b>>2)+w. With round-robin block->XCD dispatch, XCD x
// sees only slice x%4 -> 5 MB hot set per XCD L2. Lane covers 2 floats; score
// reduce spans all 64 lanes. Epilogue writes bf16 hi/lo directly (feeds gemm2).
__global__ __launch_bounds__(256) void fused_gat1(
    const float* __restrict__ hs, const float* __restrict__ hd,
    const float* __restrict__ attn, const int* __restrict__ row_off,
    const int* __restrict__ srcl,
    ushort* __restrict__ outh, ushort* __restrict__ outl) {
  int t = threadIdx.x;
  int w = t >> 6, lane = t & 63;
  int slice = blockIdx.x & 3;
  int v = (blockIdx.x >> 2) * 4 + w;
  int off = slice * 128 + lane * 2;
  int start = row_off[v];
  int deg = row_off[v + 1] - start;

  float2 a = *(const float2*)(attn + off);
  float2 hdv = *(const float2*)(hd + (size_t)v * HD + off);
  const float* hsl = hs + off;

  float ssum = 0.f;
  float2 acc = make_float2(0.f, 0.f);

  for (int base = 0; base < deg; base += 64) {
    int nc = deg - base; nc = nc < 64 ? nc : 64;
    int myidx = (lane < nc) ? srcl[start + base + lane] : 0;

    float2 c0 = {0,0}, c1 = {0,0}, c2 = {0,0}, c3 = {0,0};
    if (0 < nc) c0 = *(const float2*)(hsl + (size_t)__builtin_amdgcn_readlane(myidx, 0) * HD);
    if (1 < nc) c1 = *(const float2*)(hsl + (size_t)__builtin_amdgcn_readlane(myidx, 1) * HD);
    if (2 < nc) c2 = *(const float2*)(hsl + (size_t)__builtin_amdgcn_readlane(myidx, 2) * HD);
    if (3 < nc) c3 = *(const float2*)(hsl + (size_t)__builtin_amdgcn_readlane(myidx, 3) * HD);

    for (int i0 = 0; i0 < nc; i0 += 4) {
#define GAT1_STEP(Q, C)                                                               \
      if (i0 + Q < nc) {                                                              \
        float2 u = C;                                                                 \
        int nx = i0 + 4 + Q;                                                          \
        if (nx < nc)                                                                  \
          C = *(const float2*)(hsl + (size_t)__builtin_amdgcn_readlane(myidx, nx) * HD); \
        float e0 = u.x + hdv.x; e0 = fmaxf(e0, 0.2f * e0);                            \
        float e1 = u.y + hdv.y; e1 = fmaxf(e1, 0.2f * e1);                            \
        float part = fmaf(e0, a.x, e1 * a.y);                                         \
        _Pragma("unroll")                                                             \
        for (int k = 1; k < 64; k <<= 1) part += __shfl_xor(part, k);                 \
        float wg = __expf(part);                                                      \
        ssum += wg;                                                                   \
        acc.x = fmaf(wg, u.x, acc.x);                                                 \
        acc.y = fmaf(wg, u.y, acc.y);                                                 \
      }
      GAT1_STEP(0, c0)
      GAT1_STEP(1, c1)
      GAT1_STEP(2, c2)
      GAT1_STEP(3, c3)
#undef GAT1_STEP
    }
  }
  float inv = ssum > 0.f ? 1.f / ssum : 0.f;
  float ox = acc.x * inv, oy = acc.y * inv;
  uint bx = __float_as_uint(ox), by = __float_as_uint(oy);
  float rx = ox - __uint_as_float(bx & 0xFFFF0000u);
  float ry = oy - __uint_as_float(by & 0xFFFF0000u);
  ushort2 hv, lv;
  hv.x = (unsigned short)(bx >> 16); hv.y = (unsigned short)(by >> 16);
  lv.x = (unsigned short)(__float_as_uint(rx) >> 16);
  lv.y = (unsigned short)(__float_as_uint(ry) >> 16);
  *(ushort2*)(outh + (size_t)v * HD + off) = hv;
  *(ushort2*)(outl + (size_t)v * HD + off) = lv;
}

// ---------------- layer 2 fused: wave per node, 4 x 16-lane groups, 2-deep -----
__global__ __launch_bounds__(256) void fused_gat2(
    const float* __restrict__ hs, const float* __restrict__ hd,
    const float* __restrict__ attn, const int* __restrict__ row_off,
    const int* __restrict__ srcl, float* __restrict__ out) {
  int t = threadIdx.x;
  int w = t >> 6, lane = t & 63, grp = lane >> 4, sl = lane & 15;
  int v = blockIdx.x * 4 + w;
  int start = row_off[v];
  int deg = row_off[v + 1] - start;

  const float* ap = attn + sl * 8;
  const float* hp = hd + (size_t)v * DD + sl * 8;
  float4 a0 = *(const float4*)ap, a1 = *(const float4*)(ap + 4);
  float4 g0 = *(const float4*)hp, g1 = *(const float4*)(hp + 4);
  float areg[8] = {a0.x, a0.y, a0.z, a0.w, a1.x, a1.y, a1.z, a1.w};
  float hdreg[8] = {g0.x, g0.y, g0.z, g0.w, g1.x, g1.y, g1.z, g1.w};
  const float* hsl = hs + sl * 8;

  float ssum = 0.f;
  float acc[8] = {0.f, 0.f, 0.f, 0.f, 0.f, 0.f, 0.f, 0.f};

  float4 c0a = {0,0,0,0}, c0b = {0,0,0,0}, c1a = {0,0,0,0}, c1b = {0,0,0,0};
  if (grp < deg) { const float* p = hsl + (size_t)srcl[start + grp] * DD; c0a = *(const float4*)p; c0b = *(const float4*)(p + 4); }
  if (grp + 4 < deg) { const float* p = hsl + (size_t)srcl[start + grp + 4] * DD; c1a = *(const float4*)p; c1b = *(const float4*)(p + 4); }

  for (int i = grp; i < deg; i += 8) {
    float u0[8] = {c0a.x, c0a.y, c0a.z, c0a.w, c0b.x, c0b.y, c0b.z, c0b.w};
    float u1[8] = {c1a.x, c1a.y, c1a.z, c1a.w, c1b.x, c1b.y, c1b.z, c1b.w};
    bool have1 = (i + 4) < deg;
    if (i + 8 < deg) { const float* p = hsl + (size_t)srcl[start + i + 8] * DD; c0a = *(const float4*)p; c0b = *(const float4*)(p + 4); }
    if (i + 12 < deg) { const float* p = hsl + (size_t)srcl[start + i + 12] * DD; c1a = *(const float4*)p; c1b = *(const float4*)(p + 4); }
    float part0 = 0.f, part1 = 0.f;
#pragma unroll
    for (int j = 0; j < 8; j++) {
      float e0 = u0[j] + hdreg[j]; e0 = fmaxf(e0, 0.2f * e0);
      part0 = fmaf(e0, areg[j], part0);
      float e1 = u1[j] + hdreg[j]; e1 = fmaxf(e1, 0.2f * e1);
      part1 = fmaf(e1, areg[j], part1);
    }
#pragma unroll
    for (int k = 1; k < 16; k <<= 1) {
      part0 += __shfl_xor(part0, k);
      part1 += __shfl_xor(part1, k);
    }
    float wg0 = __expf(part0);
    float wg1 = have1 ? __expf(part1) : 0.f;
    ssum += wg0 + wg1;
#pragma unroll
    for (int j = 0; j < 8; j++)
      acc[j] = fmaf(wg0, u0[j], fmaf(wg1, u1[j], acc[j]));
  }
#pragma unroll
  for (int j = 0; j < 8; j++) {
    acc[j] += __shfl_xor(acc[j], 16);
    acc[j] += __shfl_xor(acc[j], 32);
  }
  ssum += __shfl_xor(ssum, 16);
  ssum += __shfl_xor(ssum, 32);
  float inv = ssum > 0.f ? 1.f / ssum : 0.f;
  if (lane < 16) {
    float* op = out + (size_t)v * DD + sl * 8;
    *(float4*)op = make_float4(acc[0] * inv, acc[1] * inv, acc[2] * inv, acc[3] * inv);
    *(float4*)(op + 4) = make_float4(acc[4] * inv, acc[5] * inv, acc[6] * inv, acc[7] * inv);
  }
}

// ---------------- pooling (binary search on sorted gid) + readout MLP ----------
__global__ __launch_bounds__(128) void final_kernel(
    const float* __restrict__ h2, const int* __restrict__ gid,
    const float* __restrict__ Wr1, const float* __restrict__ br1,
    const float* __restrict__ Wr2, const float* __restrict__ br2,
    float* __restrict__ out) {
  int g = blockIdx.x, t = threadIdx.x;
  int a, b;
  { int l = 0, h = N_NODES; while (l < h) { int m = (l + h) >> 1; if (gid[m] < g) l = m + 1; else h = m; } a = l; }
  { int l = a, h = N_NODES; while (l < h) { int m = (l + h) >> 1; if (gid[m] < g + 1) l = m + 1; else h = m; } b = l; }
  float s0 = 0.f, s1 = 0.f, s2 = 0.f, s3 = 0.f;
  int v = a;
  for (; v + 3 < b; v += 4) {
    s0 += h2[(size_t)(v + 0) * DD + t];
    s1 += h2[(size_t)(v + 1) * DD + t];
    s2 += h2[(size_t)(v + 2) * DD + t];
    s3 += h2[(size_t)(v + 3) * DD + t];
  }
  for (; v < b; v++) s0 += h2[(size_t)v * DD + t];
  __shared__ float hgn[128];
  float cnt = (float)(b - a);
  hgn[t] = ((s0 + s1) + (s2 + s3)) / fmaxf(cnt, 1.f);
  __syncthreads();
  if (t < 64) {
    float r = br1[t];
#pragma unroll 8
    for (int k = 0; k < 128; k++) r = fmaf(hgn[k], Wr1[k * 64 + t], r);
    r = fmaxf(r, 0.f);
    float p = r * Wr2[t];
#pragma unroll
    for (int k = 1; k < 64; k <<= 1) p += __shfl_xor(p, k);
    if (t == 0) out[g] = p + br2[0];
  }
}

extern "C" void kernel_launch(void* const* d_in, const int* in_sizes, int n_in,
                              void* d_out, int out_size, void* d_ws, size_t ws_size,
                              hipStream_t stream) {
  (void)in_sizes; (void)n_in; (void)out_size; (void)ws_size;
  const float* x     = (const float*)d_in[0];
  const float* W1s   = (const float*)d_in[1];
  const float* b1s   = (const float*)d_in[2];
  const float* W1d   = (const float*)d_in[3];
  const float* b1d   = (const float*)d_in[4];
  const float* attn1 = (const float*)d_in[5];
  const float* W2s   = (const float*)d_in[6];
  const float* b2s   = (const float*)d_in[7];
  const float* W2d   = (const float*)d_in[8];
  const float* b2d   = (const float*)d_in[9];
  const float* attn2 = (const float*)d_in[10];
  const float* Wr1   = (const float*)d_in[11];
  const float* br1   = (const float*)d_in[12];
  const float* Wr2   = (const float*)d_in[13];
  const float* br2   = (const float*)d_in[14];
  const int* src     = (const int*)d_in[15];
  const int* dst     = (const int*)d_in[16];
  const int* gid     = (const int*)d_in[17];
  float* out = (float*)d_out;

  char* ws = (char*)d_ws;
  float*  hs1     = (float*)(ws + 0);           // [10000][512] f32 (20.48 MB)
  float*  hd1     = (float*)(ws + 20480000);    // [10000][512] f32
  ushort* h1h     = (ushort*)(ws + 40960000);   // [10000][512] bf16 (10.24 MB)
  ushort* h1l     = (ushort*)(ws + 51200000);   // 10.24 MB
  ushort* xh      = (ushort*)(ws + 61440000);   // [10000][256] bf16 (5.12 MB)
  ushort* xl      = (ushort*)(ws + 66560000);   // 5.12 MB
  int*    srcl    = (int*)(ws + 71680000);      // E int (1.28 MB)
  int*    row_off = (int*)(ws + 72960000);      // N+1
  int*    cnt     = (int*)(ws + 73000064);      // N
  int*    fill    = (int*)(ws + 73040064);      // N
  ushort* b1sh    = (ushort*)(ws + 73080064);   // [512][256] bf16 (0.26 MB)
  ushort* b1sl    = (ushort*)(ws + 73342208);
  ushort* b1dh    = (ushort*)(ws + 73604352);
  ushort* b1dl    = (ushort*)(ws + 73866496);
  ushort* b2sh    = (ushort*)(ws + 74128640);   // [128][512] bf16 (0.13 MB)
  ushort* b2sl    = (ushort*)(ws + 74259712);
  ushort* b2dh    = (ushort*)(ws + 74390784);
  ushort* b2dl    = (ushort*)(ws + 74521856);
  // layer-2 reuse (hs1/hd1 regions are dead after gat1; h1h/h1l dead after gemm2)
  float*  hs2     = (float*)(ws + 0);           // [10000][128] f32 (5.12 MB)
  float*  hd2     = (float*)(ws + 5120000);
  float*  h2      = (float*)(ws + 40960000);    // over h1h after gemm2 done

  hipMemsetAsync(cnt, 0, 2 * N_NODES * 4, stream);

  hist_kernel<<<N_EDGES / 256, 256, 0, stream>>>(dst, cnt);
  scan_kernel<<<1, 1024, 0, stream>>>(cnt, row_off);
  scatter_kernel<<<N_EDGES / 256, 256, 0, stream>>>(src, dst, row_off, fill, srcl);

  // preconvert: x and weights
  split_rm<<<(N_NODES * DIM_IN / 4 + 255) / 256, 256, 0, stream>>>(x, xh, xl, N_NODES * DIM_IN / 4);
  split_tr2<<<dim3((HD * (DIM_IN / 4) + 255) / 256, 2), 256, 0, stream>>>(
      W1s, b1sh, b1sl, W1d, b1dh, b1dl, DIM_IN, HD, 9);
  split_tr2<<<dim3((DD * (HD / 4) + 255) / 256, 2), 256, 0, stream>>>(
      W2s, b2sh, b2sl, W2d, b2dh, b2dl, HD, DD, 7);

  dual_gemm_mfma<DIM_IN, HD><<<dim3(HD / 64, (N_NODES + 63) / 64), 256, 0, stream>>>(
      xh, xl, b1sh, b1sl, b1s, b1dh, b1dl, b1d, hs1, hd1, N_NODES);
  fused_gat1<<<N_NODES, 256, 0, stream>>>(hs1, hd1, attn1, row_off, srcl, h1h, h1l);

  dual_gemm_mfma<HD, DD><<<dim3(DD / 64, (N_NODES + 63) / 64), 256, 0, stream>>>(
      h1h, h1l, b2sh, b2sl, b2s, b2dh, b2dl, b2d, hs2, hd2, N_NODES);
  fused_gat2<<<(N_NODES + 3) / 4, 256, 0, stream>>>(hs2, hd2, attn2, row_off, srcl, h2);

  final_kernel<<<GG, 128, 0, stream>>>(h2, gid, Wr1, br1, Wr2, br2, out);
}

// Round 11
// 216.647 us; speedup vs baseline: 1.4596x; 1.1489x over previous
//
#include <hip/hip_runtime.h>

typedef __attribute__((ext_vector_type(8))) short bf16x8;
typedef __attribute__((ext_vector_type(4))) float f32x4;

#define N_NODES 10000
#define N_EDGES 320000
#define DIM_IN  256
#define DD      128
#define HH      4
#define HD      512
#define GG      64

// ---------------- CSR build ----------------
__global__ void hist_kernel(const int* __restrict__ dst, int* __restrict__ cnt) {
  int e = blockIdx.x * 256 + threadIdx.x;
  atomicAdd(&cnt[dst[e]], 1);
}

__global__ void scan_kernel(const int* __restrict__ cnt, int* __restrict__ row_off) {
  __shared__ int part[1024];
  int t = threadIdx.x;
  int base = t * 10;
  int s = 0;
#pragma unroll
  for (int i = 0; i < 10; i++) { int idx = base + i; if (idx < N_NODES) s += cnt[idx]; }
  part[t] = s;
  __syncthreads();
  for (int off = 1; off < 1024; off <<= 1) {
    int v = (t >= off) ? part[t - off] : 0;
    __syncthreads();
    part[t] += v;
    __syncthreads();
  }
  int run = part[t] - s;
  for (int i = 0; i < 10; i++) {
    int idx = base + i;
    if (idx < N_NODES) { row_off[idx] = run; run += cnt[idx]; }
  }
  if (t == 1023) row_off[N_NODES] = part[1023];
}

__global__ void scatter_kernel(const int* __restrict__ src, const int* __restrict__ dst,
                               const int* __restrict__ row_off,
                               int* __restrict__ fill, int* __restrict__ srcl) {
  int e = blockIdx.x * 256 + threadIdx.x;
  int d = dst[e];
  int pos = row_off[d] + atomicAdd(&fill[d], 1);
  srcl[pos] = src[e];
}

// ---------------- split-precision helpers ----------------
__device__ inline void split4(float4 v, ushort4& h, ushort4& l) {
  uint bx = __float_as_uint(v.x), by = __float_as_uint(v.y);
  uint bz = __float_as_uint(v.z), bw = __float_as_uint(v.w);
  float rx = v.x - __uint_as_float(bx & 0xFFFF0000u);
  float ry = v.y - __uint_as_float(by & 0xFFFF0000u);
  float rz = v.z - __uint_as_float(bz & 0xFFFF0000u);
  float rw = v.w - __uint_as_float(bw & 0xFFFF0000u);
  h.x = (unsigned short)(bx >> 16); h.y = (unsigned short)(by >> 16);
  h.z = (unsigned short)(bz >> 16); h.w = (unsigned short)(bw >> 16);
  l.x = (unsigned short)(__float_as_uint(rx) >> 16);
  l.y = (unsigned short)(__float_as_uint(ry) >> 16);
  l.z = (unsigned short)(__float_as_uint(rz) >> 16);
  l.w = (unsigned short)(__float_as_uint(rw) >> 16);
}

// row-major fp32 [M][K] -> bf16 hi/lo [M][K]
__global__ __launch_bounds__(256) void split_rm(const float* __restrict__ in,
                                                ushort* __restrict__ oh,
                                                ushort* __restrict__ ol, int n4) {
  int i = blockIdx.x * 256 + threadIdx.x;
  if (i >= n4) return;
  float4 v = ((const float4*)in)[i];
  ushort4 h, l;
  split4(v, h, l);
  ((ushort4*)oh)[i] = h;
  ((ushort4*)ol)[i] = l;
}

// two fp32 [K][N] -> bf16 hi/lo transposed [N][K]; blockIdx.y selects matrix
__global__ __launch_bounds__(256) void split_tr2(
    const float* __restrict__ in0, ushort* __restrict__ oh0, ushort* __restrict__ ol0,
    const float* __restrict__ in1, ushort* __restrict__ oh1, ushort* __restrict__ ol1,
    int K, int N, int lgN) {
  const float* in = blockIdx.y ? in1 : in0;
  ushort* oh = blockIdx.y ? oh1 : oh0;
  ushort* ol = blockIdx.y ? ol1 : ol0;
  int id = blockIdx.x * 256 + threadIdx.x;
  int n = id & (N - 1);
  int kq = id >> lgN;
  if (kq >= (K >> 2)) return;
  int k = kq * 4;
  float4 v;
  v.x = in[(size_t)(k + 0) * N + n];
  v.y = in[(size_t)(k + 1) * N + n];
  v.z = in[(size_t)(k + 2) * N + n];
  v.w = in[(size_t)(k + 3) * N + n];
  ushort4 h, l;
  split4(v, h, l);
  *(ushort4*)(oh + (size_t)n * K + k) = h;
  *(ushort4*)(ol + (size_t)n * K + k) = l;
}

// ---------------- dual GEMM via bf16x3 MFMA (register-prefetch pipelined) ------
template <int K, int NCOL>
__global__ __launch_bounds__(256) void dual_gemm_mfma(
    const ushort* __restrict__ Ahg, const ushort* __restrict__ Alg,
    const ushort* __restrict__ B1hg, const ushort* __restrict__ B1lg,
    const float* __restrict__ bias1,
    const ushort* __restrict__ B2hg, const ushort* __restrict__ B2lg,
    const float* __restrict__ bias2,
    float* __restrict__ C1, float* __restrict__ C2, int M) {
  __shared__ ushort Ah[64][40], Al[64][40];
  __shared__ ushort B1h[64][40], B1l[64][40], B2h[64][40], B2l[64][40];
  int t = threadIdx.x;
  int lane = t & 63, wv = t >> 6;
  int wr = wv >> 1, wc = wv & 1;
  int l15 = lane & 15, l16 = lane >> 4;
  int col0 = blockIdx.x * 64, m0 = blockIdx.y * 64;

  int sr = t >> 2;           // staging row (A) / col (B): 0..63
  int sk = (t & 3) * 8;      // staging k offset: 0,8,16,24
  bool arow_ok = (m0 + sr) < M;
  const ushort* pAh = Ahg + (size_t)(m0 + sr) * K + sk;
  const ushort* pAl = Alg + (size_t)(m0 + sr) * K + sk;
  const ushort* pB1h = B1hg + (size_t)(col0 + sr) * K + sk;
  const ushort* pB1l = B1lg + (size_t)(col0 + sr) * K + sk;
  const ushort* pB2h = B2hg + (size_t)(col0 + sr) * K + sk;
  const ushort* pB2l = B2lg + (size_t)(col0 + sr) * K + sk;

  f32x4 zero = {0.f, 0.f, 0.f, 0.f};
  f32x4 acc1[2][2], acc2[2][2];
#pragma unroll
  for (int i = 0; i < 2; i++)
#pragma unroll
    for (int j = 0; j < 2; j++) { acc1[i][j] = zero; acc2[i][j] = zero; }

  uint4 vah, val, v1h, v1l, v2h, v2l;
#define LOADK(KO)                                                            \
  vah = arow_ok ? *(const uint4*)(pAh + (KO)) : make_uint4(0u, 0u, 0u, 0u);  \
  val = arow_ok ? *(const uint4*)(pAl + (KO)) : make_uint4(0u, 0u, 0u, 0u);  \
  v1h = *(const uint4*)(pB1h + (KO));                                        \
  v1l = *(const uint4*)(pB1l + (KO));                                        \
  v2h = *(const uint4*)(pB2h + (KO));                                        \
  v2l = *(const uint4*)(pB2l + (KO));
  LOADK(0)
  for (int k0 = 0; k0 < K; k0 += 32) {
    __syncthreads();
    *(uint4*)&Ah[sr][sk] = vah;
    *(uint4*)&Al[sr][sk] = val;
    *(uint4*)&B1h[sr][sk] = v1h;
    *(uint4*)&B1l[sr][sk] = v1l;
    *(uint4*)&B2h[sr][sk] = v2h;
    *(uint4*)&B2l[sr][sk] = v2l;
    __syncthreads();
    if (k0 + 32 < K) { LOADK(k0 + 32) }   // issue next-tile loads before MFMA
#pragma unroll
    for (int cb = 0; cb < 2; cb++) {
      int bc = wc * 32 + cb * 16 + l15;
      bf16x8 b1hf = *(const bf16x8*)&B1h[bc][l16 * 8];
      bf16x8 b1lf = *(const bf16x8*)&B1l[bc][l16 * 8];
      bf16x8 b2hf = *(const bf16x8*)&B2h[bc][l16 * 8];
      bf16x8 b2lf = *(const bf16x8*)&B2l[bc][l16 * 8];
#pragma unroll
      for (int rb = 0; rb < 2; rb++) {
        int arw = wr * 32 + rb * 16 + l15;
        bf16x8 ahf = *(const bf16x8*)&Ah[arw][l16 * 8];
        bf16x8 alf = *(const bf16x8*)&Al[arw][l16 * 8];
        acc1[rb][cb] = __builtin_amdgcn_mfma_f32_16x16x32_bf16(ahf, b1hf, acc1[rb][cb], 0, 0, 0);
        acc1[rb][cb] = __builtin_amdgcn_mfma_f32_16x16x32_bf16(ahf, b1lf, acc1[rb][cb], 0, 0, 0);
        acc1[rb][cb] = __builtin_amdgcn_mfma_f32_16x16x32_bf16(alf, b1hf, acc1[rb][cb], 0, 0, 0);
        acc2[rb][cb] = __builtin_amdgcn_mfma_f32_16x16x32_bf16(ahf, b2hf, acc2[rb][cb], 0, 0, 0);
        acc2[rb][cb] = __builtin_amdgcn_mfma_f32_16x16x32_bf16(ahf, b2lf, acc2[rb][cb], 0, 0, 0);
        acc2[rb][cb] = __builtin_amdgcn_mfma_f32_16x16x32_bf16(alf, b2hf, acc2[rb][cb], 0, 0, 0);
      }
    }
  }
#undef LOADK
#pragma unroll
  for (int rb = 0; rb < 2; rb++) {
#pragma unroll
    for (int cb = 0; cb < 2; cb++) {
      int row = m0 + wr * 32 + rb * 16 + l16 * 4;
      int col = col0 + wc * 32 + cb * 16 + l15;
      float bb1 = bias1[col], bb2 = bias2[col];
#pragma unroll
      for (int rr = 0; rr < 4; rr++) {
        if (row + rr < M) {
          C1[(size_t)(row + rr) * NCOL + col] = acc1[rb][cb][rr] + bb1;
          C2[(size_t)(row + rr) * NCOL + col] = acc2[rb][cb][rr] + bb2;
        }
      }
    }
  }
}

// ---------------- layer 1 fused: XCD-pinned head-slices, 2 edges per wave ------
// Block b: slice = b & 3 (one head = 128 floats), nodes 4*(b>>2)+w.
// Lanes 0-31 = edge A, lanes 32-63 = edge B; lane covers float4 of the slice.
// Edge-pair indices via two wave-uniform readlanes + per-lane select.
// Epilogue writes bf16 hi/lo directly (feeds gemm2).
__global__ __launch_bounds__(256) void fused_gat1(
    const float* __restrict__ hs, const float* __restrict__ hd,
    const float* __restrict__ attn, const int* __restrict__ row_off,
    const int* __restrict__ srcl,
    ushort* __restrict__ outh, ushort* __restrict__ outl) {
  int t = threadIdx.x;
  int w = t >> 6, lane = t & 63;
  int slice = blockIdx.x & 3;
  int v = (blockIdx.x >> 2) * 4 + w;
  int epar = lane >> 5;                 // which edge of the pair
  int sl = lane & 31;
  int off = slice * 128 + sl * 4;
  int start = row_off[v];
  int deg = row_off[v + 1] - start;

  float4 a = *(const float4*)(attn + off);
  float4 hdv = *(const float4*)(hd + (size_t)v * HD + off);
  const float* hsl = hs + off;

  float ssum = 0.f;
  float4 acc = make_float4(0.f, 0.f, 0.f, 0.f);

  for (int base = 0; base < deg; base += 64) {
    int nc = deg - base; nc = nc < 64 ? nc : 64;
    int myidx = (lane < nc) ? srcl[start + base + lane] : 0;

    float4 c0 = {0,0,0,0}, c1 = {0,0,0,0}, c2 = {0,0,0,0}, c3 = {0,0,0,0};
#define GAT1_PRE(Q, C)                                                                \
    { int iA = 2 * Q;                                                                 \
      if (iA < nc) {                                                                  \
        int iB = iA + 1;                                                              \
        int idxA = __builtin_amdgcn_readlane(myidx, iA);                              \
        int idxB = __builtin_amdgcn_readlane(myidx, iB < nc ? iB : iA);               \
        int idx = epar ? idxB : idxA;                                                 \
        C = *(const float4*)(hsl + (size_t)idx * HD); } }
    GAT1_PRE(0, c0) GAT1_PRE(1, c1) GAT1_PRE(2, c2) GAT1_PRE(3, c3)
#undef GAT1_PRE

    for (int i0 = 0; i0 < nc; i0 += 8) {
#define GAT1_STEP(Q, C)                                                               \
      if (i0 + 2 * Q < nc) {                                                          \
        float4 u = C;                                                                 \
        int nA = i0 + 8 + 2 * Q;                                                      \
        if (nA < nc) {                                                                \
          int nB = nA + 1;                                                            \
          int idxA = __builtin_amdgcn_readlane(myidx, nA);                            \
          int idxB = __builtin_amdgcn_readlane(myidx, nB < nc ? nB : nA);             \
          int idx = epar ? idxB : idxA;                                               \
          C = *(const float4*)(hsl + (size_t)idx * HD);                               \
        }                                                                             \
        float e0 = u.x + hdv.x; e0 = fmaxf(e0, 0.2f * e0);                            \
        float e1 = u.y + hdv.y; e1 = fmaxf(e1, 0.2f * e1);                            \
        float e2 = u.z + hdv.z; e2 = fmaxf(e2, 0.2f * e2);                            \
        float e3 = u.w + hdv.w; e3 = fmaxf(e3, 0.2f * e3);                            \
        float part = fmaf(e0, a.x, fmaf(e1, a.y, fmaf(e2, a.z, e3 * a.w)));           \
        _Pragma("unroll")                                                             \
        for (int k = 1; k < 32; k <<= 1) part += __shfl_xor(part, k);                 \
        bool vld = (i0 + 2 * Q + epar) < nc;                                          \
        float wg = vld ? __expf(part) : 0.f;                                          \
        ssum += wg;                                                                   \
        acc.x = fmaf(wg, u.x, acc.x);                                                 \
        acc.y = fmaf(wg, u.y, acc.y);                                                 \
        acc.z = fmaf(wg, u.z, acc.z);                                                 \
        acc.w = fmaf(wg, u.w, acc.w);                                                 \
      }
      GAT1_STEP(0, c0)
      GAT1_STEP(1, c1)
      GAT1_STEP(2, c2)
      GAT1_STEP(3, c3)
#undef GAT1_STEP
    }
  }
  // merge the two edge streams
  acc.x += __shfl_xor(acc.x, 32);
  acc.y += __shfl_xor(acc.y, 32);
  acc.z += __shfl_xor(acc.z, 32);
  acc.w += __shfl_xor(acc.w, 32);
  ssum += __shfl_xor(ssum, 32);
  if (lane < 32) {
    float inv = ssum > 0.f ? 1.f / ssum : 0.f;
    float4 o = make_float4(acc.x * inv, acc.y * inv, acc.z * inv, acc.w * inv);
    ushort4 hv, lv;
    split4(o, hv, lv);
    *(ushort4*)(outh + (size_t)v * HD + off) = hv;
    *(ushort4*)(outl + (size_t)v * HD + off) = lv;
  }
}

// ---------------- layer 2 fused: wave per node, 4 x 16-lane groups, 2-deep -----
__global__ __launch_bounds__(256) void fused_gat2(
    const float* __restrict__ hs, const float* __restrict__ hd,
    const float* __restrict__ attn, const int* __restrict__ row_off,
    const int* __restrict__ srcl, float* __restrict__ out) {
  int t = threadIdx.x;
  int w = t >> 6, lane = t & 63, grp = lane >> 4, sl = lane & 15;
  int v = blockIdx.x * 4 + w;
  int start = row_off[v];
  int deg = row_off[v + 1] - start;

  const float* ap = attn + sl * 8;
  const float* hp = hd + (size_t)v * DD + sl * 8;
  float4 a0 = *(const float4*)ap, a1 = *(const float4*)(ap + 4);
  float4 g0 = *(const float4*)hp, g1 = *(const float4*)(hp + 4);
  float areg[8] = {a0.x, a0.y, a0.z, a0.w, a1.x, a1.y, a1.z, a1.w};
  float hdreg[8] = {g0.x, g0.y, g0.z, g0.w, g1.x, g1.y, g1.z, g1.w};
  const float* hsl = hs + sl * 8;

  float ssum = 0.f;
  float acc[8] = {0.f, 0.f, 0.f, 0.f, 0.f, 0.f, 0.f, 0.f};

  float4 c0a = {0,0,0,0}, c0b = {0,0,0,0}, c1a = {0,0,0,0}, c1b = {0,0,0,0};
  if (grp < deg) { const float* p = hsl + (size_t)srcl[start + grp] * DD; c0a = *(const float4*)p; c0b = *(const float4*)(p + 4); }
  if (grp + 4 < deg) { const float* p = hsl + (size_t)srcl[start + grp + 4] * DD; c1a = *(const float4*)p; c1b = *(const float4*)(p + 4); }

  for (int i = grp; i < deg; i += 8) {
    float u0[8] = {c0a.x, c0a.y, c0a.z, c0a.w, c0b.x, c0b.y, c0b.z, c0b.w};
    float u1[8] = {c1a.x, c1a.y, c1a.z, c1a.w, c1b.x, c1b.y, c1b.z, c1b.w};
    bool have1 = (i + 4) < deg;
    if (i + 8 < deg) { const float* p = hsl + (size_t)srcl[start + i + 8] * DD; c0a = *(const float4*)p; c0b = *(const float4*)(p + 4); }
    if (i + 12 < deg) { const float* p = hsl + (size_t)srcl[start + i + 12] * DD; c1a = *(const float4*)p; c1b = *(const float4*)(p + 4); }
    float part0 = 0.f, part1 = 0.f;
#pragma unroll
    for (int j = 0; j < 8; j++) {
      float e0 = u0[j] + hdreg[j]; e0 = fmaxf(e0, 0.2f * e0);
      part0 = fmaf(e0, areg[j], part0);
      float e1 = u1[j] + hdreg[j]; e1 = fmaxf(e1, 0.2f * e1);
      part1 = fmaf(e1, areg[j], part1);
    }
#pragma unroll
    for (int k = 1; k < 16; k <<= 1) {
      part0 += __shfl_xor(part0, k);
      part1 += __shfl_xor(part1, k);
    }
    float wg0 = __expf(part0);
    float wg1 = have1 ? __expf(part1) : 0.f;
    ssum += wg0 + wg1;
#pragma unroll
    for (int j = 0; j < 8; j++)
      acc[j] = fmaf(wg0, u0[j], fmaf(wg1, u1[j], acc[j]));
  }
#pragma unroll
  for (int j = 0; j < 8; j++) {
    acc[j] += __shfl_xor(acc[j], 16);
    acc[j] += __shfl_xor(acc[j], 32);
  }
  ssum += __shfl_xor(ssum, 16);
  ssum += __shfl_xor(ssum, 32);
  float inv = ssum > 0.f ? 1.f / ssum : 0.f;
  if (lane < 16) {
    float* op = out + (size_t)v * DD + sl * 8;
    *(float4*)op = make_float4(acc[0] * inv, acc[1] * inv, acc[2] * inv, acc[3] * inv);
    *(float4*)(op + 4) = make_float4(acc[4] * inv, acc[5] * inv, acc[6] * inv, acc[7] * inv);
  }
}

// ---------------- pooling (binary search on sorted gid) + readout MLP ----------
__global__ __launch_bounds__(128) void final_kernel(
    const float* __restrict__ h2, const int* __restrict__ gid,
    const float* __restrict__ Wr1, const float* __restrict__ br1,
    const float* __restrict__ Wr2, const float* __restrict__ br2,
    float* __restrict__ out) {
  int g = blockIdx.x, t = threadIdx.x;
  int a, b;
  { int l = 0, h = N_NODES; while (l < h) { int m = (l + h) >> 1; if (gid[m] < g) l = m + 1; else h = m; } a = l; }
  { int l = a, h = N_NODES; while (l < h) { int m = (l + h) >> 1; if (gid[m] < g + 1) l = m + 1; else h = m; } b = l; }
  float s0 = 0.f, s1 = 0.f, s2 = 0.f, s3 = 0.f;
  int v = a;
  for (; v + 3 < b; v += 4) {
    s0 += h2[(size_t)(v + 0) * DD + t];
    s1 += h2[(size_t)(v + 1) * DD + t];
    s2 += h2[(size_t)(v + 2) * DD + t];
    s3 += h2[(size_t)(v + 3) * DD + t];
  }
  for (; v < b; v++) s0 += h2[(size_t)v * DD + t];
  __shared__ float hgn[128];
  float cnt = (float)(b - a);
  hgn[t] = ((s0 + s1) + (s2 + s3)) / fmaxf(cnt, 1.f);
  __syncthreads();
  if (t < 64) {
    float r = br1[t];
#pragma unroll 8
    for (int k = 0; k < 128; k++) r = fmaf(hgn[k], Wr1[k * 64 + t], r);
    r = fmaxf(r, 0.f);
    float p = r * Wr2[t];
#pragma unroll
    for (int k = 1; k < 64; k <<= 1) p += __shfl_xor(p, k);
    if (t == 0) out[g] = p + br2[0];
  }
}

extern "C" void kernel_launch(void* const* d_in, const int* in_sizes, int n_in,
                              void* d_out, int out_size, void* d_ws, size_t ws_size,
                              hipStream_t stream) {
  (void)in_sizes; (void)n_in; (void)out_size; (void)ws_size;
  const float* x     = (const float*)d_in[0];
  const float* W1s   = (const float*)d_in[1];
  const float* b1s   = (const float*)d_in[2];
  const float* W1d   = (const float*)d_in[3];
  const float* b1d   = (const float*)d_in[4];
  const float* attn1 = (const float*)d_in[5];
  const float* W2s   = (const float*)d_in[6];
  const float* b2s   = (const float*)d_in[7];
  const float* W2d   = (const float*)d_in[8];
  const float* b2d   = (const float*)d_in[9];
  const float* attn2 = (const float*)d_in[10];
  const float* Wr1   = (const float*)d_in[11];
  const float* br1   = (const float*)d_in[12];
  const float* Wr2   = (const float*)d_in[13];
  const float* br2   = (const float*)d_in[14];
  const int* src     = (const int*)d_in[15];
  const int* dst     = (const int*)d_in[16];
  const int* gid     = (const int*)d_in[17];
  float* out = (float*)d_out;

  char* ws = (char*)d_ws;
  float*  hs1     = (float*)(ws + 0);           // [10000][512] f32 (20.48 MB)
  float*  hd1     = (float*)(ws + 20480000);    // [10000][512] f32
  ushort* h1h     = (ushort*)(ws + 40960000);   // [10000][512] bf16 (10.24 MB)
  ushort* h1l     = (ushort*)(ws + 51200000);   // 10.24 MB
  ushort* xh      = (ushort*)(ws + 61440000);   // [10000][256] bf16 (5.12 MB)
  ushort* xl      = (ushort*)(ws + 66560000);   // 5.12 MB
  int*    srcl    = (int*)(ws + 71680000);      // E int (1.28 MB)
  int*    row_off = (int*)(ws + 72960000);      // N+1
  int*    cnt     = (int*)(ws + 73000064);      // N
  int*    fill    = (int*)(ws + 73040064);      // N
  ushort* b1sh    = (ushort*)(ws + 73080064);   // [512][256] bf16 (0.26 MB)
  ushort* b1sl    = (ushort*)(ws + 73342208);
  ushort* b1dh    = (ushort*)(ws + 73604352);
  ushort* b1dl    = (ushort*)(ws + 73866496);
  ushort* b2sh    = (ushort*)(ws + 74128640);   // [128][512] bf16 (0.13 MB)
  ushort* b2sl    = (ushort*)(ws + 74259712);
  ushort* b2dh    = (ushort*)(ws + 74390784);
  ushort* b2dl    = (ushort*)(ws + 74521856);
  // layer-2 reuse (hs1/hd1 regions are dead after gat1; h1h/h1l dead after gemm2)
  float*  hs2     = (float*)(ws + 0);           // [10000][128] f32 (5.12 MB)
  float*  hd2     = (float*)(ws + 5120000);
  float*  h2      = (float*)(ws + 40960000);    // over h1h after gemm2 done

  hipMemsetAsync(cnt, 0, 2 * N_NODES * 4, stream);

  hist_kernel<<<N_EDGES / 256, 256, 0, stream>>>(dst, cnt);
  scan_kernel<<<1, 1024, 0, stream>>>(cnt, row_off);
  scatter_kernel<<<N_EDGES / 256, 256, 0, stream>>>(src, dst, row_off, fill, srcl);

  // preconvert: x and weights
  split_rm<<<(N_NODES * DIM_IN / 4 + 255) / 256, 256, 0, stream>>>(x, xh, xl, N_NODES * DIM_IN / 4);
  split_tr2<<<dim3((HD * (DIM_IN / 4) + 255) / 256, 2), 256, 0, stream>>>(
      W1s, b1sh, b1sl, W1d, b1dh, b1dl, DIM_IN, HD, 9);
  split_tr2<<<dim3((DD * (HD / 4) + 255) / 256, 2), 256, 0, stream>>>(
      W2s, b2sh, b2sl, W2d, b2dh, b2dl, HD, DD, 7);

  dual_gemm_mfma<DIM_IN, HD><<<dim3(HD / 64, (N_NODES + 63) / 64), 256, 0, stream>>>(
      xh, xl, b1sh, b1sl, b1s, b1dh, b1dl, b1d, hs1, hd1, N_NODES);
  fused_gat1<<<N_NODES, 256, 0, stream>>>(hs1, hd1, attn1, row_off, srcl, h1h, h1l);

  dual_gemm_mfma<HD, DD><<<dim3(DD / 64, (N_NODES + 63) / 64), 256, 0, stream>>>(
      h1h, h1l, b2sh, b2sl, b2s, b2dh, b2dl, b2d, hs2, hd2, N_NODES);
  fused_gat2<<<(N_NODES + 3) / 4, 256, 0, stream>>>(hs2, hd2, attn2, row_off, srcl, h2);

  final_kernel<<<GG, 128, 0, stream>>>(h2, gid, Wr1, br1, Wr2, br2, out);
}

// Round 13
// 212.020 us; speedup vs baseline: 1.4915x; 1.0218x over previous
//
#include <hip/hip_runtime.h>

typedef __attribute__((ext_vector_type(8))) short bf16x8;
typedef __attribute__((ext_vector_type(4))) float f32x4;

#define N_NODES 10000
#define N_EDGES 320000
#define DIM_IN  256
#define DD      128
#define HH      4
#define HD      512
#define GG      64

// ---------------- CSR build ----------------
__global__ void hist_kernel(const int* __restrict__ dst, int* __restrict__ cnt) {
  int e = blockIdx.x * 256 + threadIdx.x;
  atomicAdd(&cnt[dst[e]], 1);
}

__global__ void scan_kernel(const int* __restrict__ cnt, int* __restrict__ row_off) {
  __shared__ int part[1024];
  int t = threadIdx.x;
  int base = t * 10;
  int s = 0;
#pragma unroll
  for (int i = 0; i < 10; i++) { int idx = base + i; if (idx < N_NODES) s += cnt[idx]; }
  part[t] = s;
  __syncthreads();
  for (int off = 1; off < 1024; off <<= 1) {
    int v = (t >= off) ? part[t - off] : 0;
    __syncthreads();
    part[t] += v;
    __syncthreads();
  }
  int run = part[t] - s;
  for (int i = 0; i < 10; i++) {
    int idx = base + i;
    if (idx < N_NODES) { row_off[idx] = run; run += cnt[idx]; }
  }
  if (t == 1023) row_off[N_NODES] = part[1023];
}

__global__ void scatter_kernel(const int* __restrict__ src, const int* __restrict__ dst,
                               const int* __restrict__ row_off,
                               int* __restrict__ fill, int* __restrict__ srcl) {
  int e = blockIdx.x * 256 + threadIdx.x;
  int d = dst[e];
  int pos = row_off[d] + atomicAdd(&fill[d], 1);
  srcl[pos] = src[e];
}

// ---------------- split-precision helpers ----------------
__device__ inline void split4(float4 v, ushort4& h, ushort4& l) {
  uint bx = __float_as_uint(v.x), by = __float_as_uint(v.y);
  uint bz = __float_as_uint(v.z), bw = __float_as_uint(v.w);
  float rx = v.x - __uint_as_float(bx & 0xFFFF0000u);
  float ry = v.y - __uint_as_float(by & 0xFFFF0000u);
  float rz = v.z - __uint_as_float(bz & 0xFFFF0000u);
  float rw = v.w - __uint_as_float(bw & 0xFFFF0000u);
  h.x = (unsigned short)(bx >> 16); h.y = (unsigned short)(by >> 16);
  h.z = (unsigned short)(bz >> 16); h.w = (unsigned short)(bw >> 16);
  l.x = (unsigned short)(__float_as_uint(rx) >> 16);
  l.y = (unsigned short)(__float_as_uint(ry) >> 16);
  l.z = (unsigned short)(__float_as_uint(rz) >> 16);
  l.w = (unsigned short)(__float_as_uint(rw) >> 16);
}

// row-major fp32 [M][K] -> bf16 hi/lo [M][K]
__global__ __launch_bounds__(256) void split_rm(const float* __restrict__ in,
                                                ushort* __restrict__ oh,
                                                ushort* __restrict__ ol, int n4) {
  int i = blockIdx.x * 256 + threadIdx.x;
  if (i >= n4) return;
  float4 v = ((const float4*)in)[i];
  ushort4 h, l;
  split4(v, h, l);
  ((ushort4*)oh)[i] = h;
  ((ushort4*)ol)[i] = l;
}

// two fp32 [K][N] -> bf16 hi/lo transposed [N][K]; blockIdx.y selects matrix
__global__ __launch_bounds__(256) void split_tr2(
    const float* __restrict__ in0, ushort* __restrict__ oh0, ushort* __restrict__ ol0,
    const float* __restrict__ in1, ushort* __restrict__ oh1, ushort* __restrict__ ol1,
    int K, int N, int lgN) {
  const float* in = blockIdx.y ? in1 : in0;
  ushort* oh = blockIdx.y ? oh1 : oh0;
  ushort* ol = blockIdx.y ? ol1 : ol0;
  int id = blockIdx.x * 256 + threadIdx.x;
  int n = id & (N - 1);
  int kq = id >> lgN;
  if (kq >= (K >> 2)) return;
  int k = kq * 4;
  float4 v;
  v.x = in[(size_t)(k + 0) * N + n];
  v.y = in[(size_t)(k + 1) * N + n];
  v.z = in[(size_t)(k + 2) * N + n];
  v.w = in[(size_t)(k + 3) * N + n];
  ushort4 h, l;
  split4(v, h, l);
  *(ushort4*)(oh + (size_t)n * K + k) = h;
  *(ushort4*)(ol + (size_t)n * K + k) = l;
}

// ---------------- dual GEMM via bf16x3 MFMA (register-prefetch pipelined) ------
template <int K, int NCOL>
__global__ __launch_bounds__(256) void dual_gemm_mfma(
    const ushort* __restrict__ Ahg, const ushort* __restrict__ Alg,
    const ushort* __restrict__ B1hg, const ushort* __restrict__ B1lg,
    const float* __restrict__ bias1,
    const ushort* __restrict__ B2hg, const ushort* __restrict__ B2lg,
    const float* __restrict__ bias2,
    float* __restrict__ C1, float* __restrict__ C2, int M) {
  __shared__ ushort Ah[64][40], Al[64][40];
  __shared__ ushort B1h[64][40], B1l[64][40], B2h[64][40], B2l[64][40];
  int t = threadIdx.x;
  int lane = t & 63, wv = t >> 6;
  int wr = wv >> 1, wc = wv & 1;
  int l15 = lane & 15, l16 = lane >> 4;
  int col0 = blockIdx.x * 64, m0 = blockIdx.y * 64;

  int sr = t >> 2;           // staging row (A) / col (B): 0..63
  int sk = (t & 3) * 8;      // staging k offset: 0,8,16,24
  bool arow_ok = (m0 + sr) < M;
  const ushort* pAh = Ahg + (size_t)(m0 + sr) * K + sk;
  const ushort* pAl = Alg + (size_t)(m0 + sr) * K + sk;
  const ushort* pB1h = B1hg + (size_t)(col0 + sr) * K + sk;
  const ushort* pB1l = B1lg + (size_t)(col0 + sr) * K + sk;
  const ushort* pB2h = B2hg + (size_t)(col0 + sr) * K + sk;
  const ushort* pB2l = B2lg + (size_t)(col0 + sr) * K + sk;

  f32x4 zero = {0.f, 0.f, 0.f, 0.f};
  f32x4 acc1[2][2], acc2[2][2];
#pragma unroll
  for (int i = 0; i < 2; i++)
#pragma unroll
    for (int j = 0; j < 2; j++) { acc1[i][j] = zero; acc2[i][j] = zero; }

  uint4 vah, val, v1h, v1l, v2h, v2l;
#define LOADK(KO)                                                            \
  vah = arow_ok ? *(const uint4*)(pAh + (KO)) : make_uint4(0u, 0u, 0u, 0u);  \
  val = arow_ok ? *(const uint4*)(pAl + (KO)) : make_uint4(0u, 0u, 0u, 0u);  \
  v1h = *(const uint4*)(pB1h + (KO));                                        \
  v1l = *(const uint4*)(pB1l + (KO));                                        \
  v2h = *(const uint4*)(pB2h + (KO));                                        \
  v2l = *(const uint4*)(pB2l + (KO));
  LOADK(0)
  for (int k0 = 0; k0 < K; k0 += 32) {
    __syncthreads();
    *(uint4*)&Ah[sr][sk] = vah;
    *(uint4*)&Al[sr][sk] = val;
    *(uint4*)&B1h[sr][sk] = v1h;
    *(uint4*)&B1l[sr][sk] = v1l;
    *(uint4*)&B2h[sr][sk] = v2h;
    *(uint4*)&B2l[sr][sk] = v2l;
    __syncthreads();
    if (k0 + 32 < K) { LOADK(k0 + 32) }   // issue next-tile loads before MFMA
#pragma unroll
    for (int cb = 0; cb < 2; cb++) {
      int bc = wc * 32 + cb * 16 + l15;
      bf16x8 b1hf = *(const bf16x8*)&B1h[bc][l16 * 8];
      bf16x8 b1lf = *(const bf16x8*)&B1l[bc][l16 * 8];
      bf16x8 b2hf = *(const bf16x8*)&B2h[bc][l16 * 8];
      bf16x8 b2lf = *(const bf16x8*)&B2l[bc][l16 * 8];
#pragma unroll
      for (int rb = 0; rb < 2; rb++) {
        int arw = wr * 32 + rb * 16 + l15;
        bf16x8 ahf = *(const bf16x8*)&Ah[arw][l16 * 8];
        bf16x8 alf = *(const bf16x8*)&Al[arw][l16 * 8];
        acc1[rb][cb] = __builtin_amdgcn_mfma_f32_16x16x32_bf16(ahf, b1hf, acc1[rb][cb], 0, 0, 0);
        acc1[rb][cb] = __builtin_amdgcn_mfma_f32_16x16x32_bf16(ahf, b1lf, acc1[rb][cb], 0, 0, 0);
        acc1[rb][cb] = __builtin_amdgcn_mfma_f32_16x16x32_bf16(alf, b1hf, acc1[rb][cb], 0, 0, 0);
        acc2[rb][cb] = __builtin_amdgcn_mfma_f32_16x16x32_bf16(ahf, b2hf, acc2[rb][cb], 0, 0, 0);
        acc2[rb][cb] = __builtin_amdgcn_mfma_f32_16x16x32_bf16(ahf, b2lf, acc2[rb][cb], 0, 0, 0);
        acc2[rb][cb] = __builtin_amdgcn_mfma_f32_16x16x32_bf16(alf, b2hf, acc2[rb][cb], 0, 0, 0);
      }
    }
  }
#undef LOADK
#pragma unroll
  for (int rb = 0; rb < 2; rb++) {
#pragma unroll
    for (int cb = 0; cb < 2; cb++) {
      int row = m0 + wr * 32 + rb * 16 + l16 * 4;
      int col = col0 + wc * 32 + cb * 16 + l15;
      float bb1 = bias1[col], bb2 = bias2[col];
#pragma unroll
      for (int rr = 0; rr < 4; rr++) {
        if (row + rr < M) {
          C1[(size_t)(row + rr) * NCOL + col] = acc1[rb][cb][rr] + bb1;
          C2[(size_t)(row + rr) * NCOL + col] = acc2[rb][cb][rr] + bb2;
        }
      }
    }
  }
}

// ---------------- layer 1 fused: XCD-pinned head-slices, 4 edges per step ------
// Block b: slice = b & 3 (one head = 128 floats), nodes 4*(b>>2)+w.
// Wave = 4 x 16-lane groups; group owns one edge; lane covers 8 floats.
// EXEC-SAFETY: every __shfl on myidx executes UNCONDITIONALLY by all 64 lanes
// with a clamped index (ds_bpermute from an inactive lane is undefined — the
// r7/r12 corruption). Only the loads and exp-validity are guarded.
__global__ __launch_bounds__(256) void fused_gat1(
    const float* __restrict__ hs, const float* __restrict__ hd,
    const float* __restrict__ attn, const int* __restrict__ row_off,
    const int* __restrict__ srcl,
    ushort* __restrict__ outh, ushort* __restrict__ outl) {
  int t = threadIdx.x;
  int w = t >> 6, lane = t & 63;
  int slice = blockIdx.x & 3;
  int v = (blockIdx.x >> 2) * 4 + w;
  int grp = lane >> 4, sl = lane & 15;
  int off = slice * 128 + sl * 8;
  int start = row_off[v];
  int deg = row_off[v + 1] - start;

  const float* ap = attn + off;
  const float* hp = hd + (size_t)v * HD + off;
  float4 a0 = *(const float4*)ap, a1 = *(const float4*)(ap + 4);
  float4 g0 = *(const float4*)hp, g1 = *(const float4*)(hp + 4);
  float areg[8] = {a0.x, a0.y, a0.z, a0.w, a1.x, a1.y, a1.z, a1.w};
  float hdreg[8] = {g0.x, g0.y, g0.z, g0.w, g1.x, g1.y, g1.z, g1.w};
  const float* hsl = hs + off;

  float ssum = 0.f;
  float acc[8] = {0.f, 0.f, 0.f, 0.f, 0.f, 0.f, 0.f, 0.f};

  for (int base = 0; base < deg; base += 64) {
    int nc = deg - base; nc = nc < 64 ? nc : 64;
    // one coalesced index load per 64-edge chunk
    int myidx = (lane < nc) ? srcl[start + base + lane] : 0;

    // 2-deep pipeline: buffer A = edges i0+grp, buffer B = edges i0+4+grp
    float4 cAa = {0,0,0,0}, cAb = {0,0,0,0}, cBa = {0,0,0,0}, cBb = {0,0,0,0};
    {
      int eA = grp, eB = grp + 4;
      int idxA = __shfl(myidx, eA < nc ? eA : 0);   // unconditional shfl
      int idxB = __shfl(myidx, eB < nc ? eB : 0);   // unconditional shfl
      if (eA < nc) { const float* p = hsl + (size_t)idxA * HD; cAa = *(const float4*)p; cAb = *(const float4*)(p + 4); }
      if (eB < nc) { const float* p = hsl + (size_t)idxB * HD; cBa = *(const float4*)p; cBb = *(const float4*)(p + 4); }
    }

    for (int i0 = 0; i0 < nc; i0 += 8) {
#define GAT1_STEP(S, CA, CB)                                                   \
      { int e = i0 + 4 * S + grp;                                              \
        int nx = i0 + 8 + 4 * S + grp;                                         \
        int nidx = __shfl(myidx, nx < nc ? nx : 0);  /* unconditional shfl */  \
        bool vld = e < nc;                                                     \
        float u[8] = {CA.x, CA.y, CA.z, CA.w, CB.x, CB.y, CB.z, CB.w};         \
        if (nx < nc) {                                                         \
          const float* p = hsl + (size_t)nidx * HD;                            \
          CA = *(const float4*)p; CB = *(const float4*)(p + 4);                \
        }                                                                      \
        float part = 0.f;                                                      \
        _Pragma("unroll")                                                      \
        for (int j = 0; j < 8; j++) {                                          \
          float ee = u[j] + hdreg[j];                                          \
          ee = fmaxf(ee, 0.2f * ee);                                           \
          part = fmaf(ee, areg[j], part);                                      \
        }                                                                      \
        _Pragma("unroll")                                                      \
        for (int k = 1; k < 16; k <<= 1) part += __shfl_xor(part, k);          \
        float wg = vld ? __expf(part) : 0.f;                                   \
        ssum += wg;                                                            \
        _Pragma("unroll")                                                      \
        for (int j = 0; j < 8; j++) acc[j] = fmaf(wg, u[j], acc[j]);           \
      }
      GAT1_STEP(0, cAa, cAb)
      GAT1_STEP(1, cBa, cBb)
#undef GAT1_STEP
    }
  }
  // merge the 4 groups
#pragma unroll
  for (int j = 0; j < 8; j++) {
    acc[j] += __shfl_xor(acc[j], 16);
    acc[j] += __shfl_xor(acc[j], 32);
  }
  ssum += __shfl_xor(ssum, 16);
  ssum += __shfl_xor(ssum, 32);
  if (lane < 16) {
    float inv = ssum > 0.f ? 1.f / ssum : 0.f;
    float4 o0 = make_float4(acc[0] * inv, acc[1] * inv, acc[2] * inv, acc[3] * inv);
    float4 o1 = make_float4(acc[4] * inv, acc[5] * inv, acc[6] * inv, acc[7] * inv);
    ushort4 hv0, lv0, hv1, lv1;
    split4(o0, hv0, lv0);
    split4(o1, hv1, lv1);
    *(ushort4*)(outh + (size_t)v * HD + off) = hv0;
    *(ushort4*)(outh + (size_t)v * HD + off + 4) = hv1;
    *(ushort4*)(outl + (size_t)v * HD + off) = lv0;
    *(ushort4*)(outl + (size_t)v * HD + off + 4) = lv1;
  }
}

// ---------------- layer 2 fused: wave per node, 4 x 16-lane groups, 2-deep -----
__global__ __launch_bounds__(256) void fused_gat2(
    const float* __restrict__ hs, const float* __restrict__ hd,
    const float* __restrict__ attn, const int* __restrict__ row_off,
    const int* __restrict__ srcl, float* __restrict__ out) {
  int t = threadIdx.x;
  int w = t >> 6, lane = t & 63, grp = lane >> 4, sl = lane & 15;
  int v = blockIdx.x * 4 + w;
  int start = row_off[v];
  int deg = row_off[v + 1] - start;

  const float* ap = attn + sl * 8;
  const float* hp = hd + (size_t)v * DD + sl * 8;
  float4 a0 = *(const float4*)ap, a1 = *(const float4*)(ap + 4);
  float4 g0 = *(const float4*)hp, g1 = *(const float4*)(hp + 4);
  float areg[8] = {a0.x, a0.y, a0.z, a0.w, a1.x, a1.y, a1.z, a1.w};
  float hdreg[8] = {g0.x, g0.y, g0.z, g0.w, g1.x, g1.y, g1.z, g1.w};
  const float* hsl = hs + sl * 8;

  float ssum = 0.f;
  float acc[8] = {0.f, 0.f, 0.f, 0.f, 0.f, 0.f, 0.f, 0.f};

  float4 c0a = {0,0,0,0}, c0b = {0,0,0,0}, c1a = {0,0,0,0}, c1b = {0,0,0,0};
  if (grp < deg) { const float* p = hsl + (size_t)srcl[start + grp] * DD; c0a = *(const float4*)p; c0b = *(const float4*)(p + 4); }
  if (grp + 4 < deg) { const float* p = hsl + (size_t)srcl[start + grp + 4] * DD; c1a = *(const float4*)p; c1b = *(const float4*)(p + 4); }

  for (int i = grp; i < deg; i += 8) {
    float u0[8] = {c0a.x, c0a.y, c0a.z, c0a.w, c0b.x, c0b.y, c0b.z, c0b.w};
    float u1[8] = {c1a.x, c1a.y, c1a.z, c1a.w, c1b.x, c1b.y, c1b.z, c1b.w};
    bool have1 = (i + 4) < deg;
    if (i + 8 < deg) { const float* p = hsl + (size_t)srcl[start + i + 8] * DD; c0a = *(const float4*)p; c0b = *(const float4*)(p + 4); }
    if (i + 12 < deg) { const float* p = hsl + (size_t)srcl[start + i + 12] * DD; c1a = *(const float4*)p; c1b = *(const float4*)(p + 4); }
    float part0 = 0.f, part1 = 0.f;
#pragma unroll
    for (int j = 0; j < 8; j++) {
      float e0 = u0[j] + hdreg[j]; e0 = fmaxf(e0, 0.2f * e0);
      part0 = fmaf(e0, areg[j], part0);
      float e1 = u1[j] + hdreg[j]; e1 = fmaxf(e1, 0.2f * e1);
      part1 = fmaf(e1, areg[j], part1);
    }
#pragma unroll
    for (int k = 1; k < 16; k <<= 1) {
      part0 += __shfl_xor(part0, k);
      part1 += __shfl_xor(part1, k);
    }
    float wg0 = __expf(part0);
    float wg1 = have1 ? __expf(part1) : 0.f;
    ssum += wg0 + wg1;
#pragma unroll
    for (int j = 0; j < 8; j++)
      acc[j] = fmaf(wg0, u0[j], fmaf(wg1, u1[j], acc[j]));
  }
#pragma unroll
  for (int j = 0; j < 8; j++) {
    acc[j] += __shfl_xor(acc[j], 16);
    acc[j] += __shfl_xor(acc[j], 32);
  }
  ssum += __shfl_xor(ssum, 16);
  ssum += __shfl_xor(ssum, 32);
  float inv = ssum > 0.f ? 1.f / ssum : 0.f;
  if (lane < 16) {
    float* op = out + (size_t)v * DD + sl * 8;
    *(float4*)op = make_float4(acc[0] * inv, acc[1] * inv, acc[2] * inv, acc[3] * inv);
    *(float4*)(op + 4) = make_float4(acc[4] * inv, acc[5] * inv, acc[6] * inv, acc[7] * inv);
  }
}

// ---------------- pooling (binary search on sorted gid) + readout MLP ----------
__global__ __launch_bounds__(128) void final_kernel(
    const float* __restrict__ h2, const int* __restrict__ gid,
    const float* __restrict__ Wr1, const float* __restrict__ br1,
    const float* __restrict__ Wr2, const float* __restrict__ br2,
    float* __restrict__ out) {
  int g = blockIdx.x, t = threadIdx.x;
  int a, b;
  { int l = 0, h = N_NODES; while (l < h) { int m = (l + h) >> 1; if (gid[m] < g) l = m + 1; else h = m; } a = l; }
  { int l = a, h = N_NODES; while (l < h) { int m = (l + h) >> 1; if (gid[m] < g + 1) l = m + 1; else h = m; } b = l; }
  float s0 = 0.f, s1 = 0.f, s2 = 0.f, s3 = 0.f;
  int v = a;
  for (; v + 3 < b; v += 4) {
    s0 += h2[(size_t)(v + 0) * DD + t];
    s1 += h2[(size_t)(v + 1) * DD + t];
    s2 += h2[(size_t)(v + 2) * DD + t];
    s3 += h2[(size_t)(v + 3) * DD + t];
  }
  for (; v < b; v++) s0 += h2[(size_t)v * DD + t];
  __shared__ float hgn[128];
  float cnt = (float)(b - a);
  hgn[t] = ((s0 + s1) + (s2 + s3)) / fmaxf(cnt, 1.f);
  __syncthreads();
  if (t < 64) {
    float r = br1[t];
#pragma unroll 8
    for (int k = 0; k < 128; k++) r = fmaf(hgn[k], Wr1[k * 64 + t], r);
    r = fmaxf(r, 0.f);
    float p = r * Wr2[t];
#pragma unroll
    for (int k = 1; k < 64; k <<= 1) p += __shfl_xor(p, k);
    if (t == 0) out[g] = p + br2[0];
  }
}

extern "C" void kernel_launch(void* const* d_in, const int* in_sizes, int n_in,
                              void* d_out, int out_size, void* d_ws, size_t ws_size,
                              hipStream_t stream) {
  (void)in_sizes; (void)n_in; (void)out_size; (void)ws_size;
  const float* x     = (const float*)d_in[0];
  const float* W1s   = (const float*)d_in[1];
  const float* b1s   = (const float*)d_in[2];
  const float* W1d   = (const float*)d_in[3];
  const float* b1d   = (const float*)d_in[4];
  const float* attn1 = (const float*)d_in[5];
  const float* W2s   = (const float*)d_in[6];
  const float* b2s   = (const float*)d_in[7];
  const float* W2d   = (const float*)d_in[8];
  const float* b2d   = (const float*)d_in[9];
  const float* attn2 = (const float*)d_in[10];
  const float* Wr1   = (const float*)d_in[11];
  const float* br1   = (const float*)d_in[12];
  const float* Wr2   = (const float*)d_in[13];
  const float* br2   = (const float*)d_in[14];
  const int* src     = (const int*)d_in[15];
  const int* dst     = (const int*)d_in[16];
  const int* gid     = (const int*)d_in[17];
  float* out = (float*)d_out;

  char* ws = (char*)d_ws;
  float*  hs1     = (float*)(ws + 0);           // [10000][512] f32 (20.48 MB)
  float*  hd1     = (float*)(ws + 20480000);    // [10000][512] f32
  ushort* h1h     = (ushort*)(ws + 40960000);   // [10000][512] bf16 (10.24 MB)
  ushort* h1l     = (ushort*)(ws + 51200000);   // 10.24 MB
  ushort* xh      = (ushort*)(ws + 61440000);   // [10000][256] bf16 (5.12 MB)
  ushort* xl      = (ushort*)(ws + 66560000);   // 5.12 MB
  int*    srcl    = (int*)(ws + 71680000);      // E int (1.28 MB)
  int*    row_off = (int*)(ws + 72960000);      // N+1
  int*    cnt     = (int*)(ws + 73000064);      // N
  int*    fill    = (int*)(ws + 73040064);      // N
  ushort* b1sh    = (ushort*)(ws + 73080064);   // [512][256] bf16 (0.26 MB)
  ushort* b1sl    = (ushort*)(ws + 73342208);
  ushort* b1dh    = (ushort*)(ws + 73604352);
  ushort* b1dl    = (ushort*)(ws + 73866496);
  ushort* b2sh    = (ushort*)(ws + 74128640);   // [128][512] bf16 (0.13 MB)
  ushort* b2sl    = (ushort*)(ws + 74259712);
  ushort* b2dh    = (ushort*)(ws + 74390784);
  ushort* b2dl    = (ushort*)(ws + 74521856);
  // layer-2 reuse (hs1/hd1 regions are dead after gat1; h1h/h1l dead after gemm2)
  float*  hs2     = (float*)(ws + 0);           // [10000][128] f32 (5.12 MB)
  float*  hd2     = (float*)(ws + 5120000);
  float*  h2      = (float*)(ws + 40960000);    // over h1h after gemm2 done

  hipMemsetAsync(cnt, 0, 2 * N_NODES * 4, stream);

  hist_kernel<<<N_EDGES / 256, 256, 0, stream>>>(dst, cnt);
  scan_kernel<<<1, 1024, 0, stream>>>(cnt, row_off);
  scatter_kernel<<<N_EDGES / 256, 256, 0, stream>>>(src, dst, row_off, fill, srcl);

  // preconvert: x and weights
  split_rm<<<(N_NODES * DIM_IN / 4 + 255) / 256, 256, 0, stream>>>(x, xh, xl, N_NODES * DIM_IN / 4);
  split_tr2<<<dim3((HD * (DIM_IN / 4) + 255) / 256, 2), 256, 0, stream>>>(
      W1s, b1sh, b1sl, W1d, b1dh, b1dl, DIM_IN, HD, 9);
  split_tr2<<<dim3((DD * (HD / 4) + 255) / 256, 2), 256, 0, stream>>>(
      W2s, b2sh, b2sl, W2d, b2dh, b2dl, HD, DD, 7);

  dual_gemm_mfma<DIM_IN, HD><<<dim3(HD / 64, (N_NODES + 63) / 64), 256, 0, stream>>>(
      xh, xl, b1sh, b1sl, b1s, b1dh, b1dl, b1d, hs1, hd1, N_NODES);
  fused_gat1<<<N_NODES, 256, 0, stream>>>(hs1, hd1, attn1, row_off, srcl, h1h, h1l);

  dual_gemm_mfma<HD, DD><<<dim3(DD / 64, (N_NODES + 63) / 64), 256, 0, stream>>>(
      h1h, h1l, b2sh, b2sl, b2s, b2dh, b2dl, b2d, hs2, hd2, N_NODES);
  fused_gat2<<<(N_NODES + 3) / 4, 256, 0, stream>>>(hs2, hd2, attn2, row_off, srcl, h2);

  final_kernel<<<GG, 128, 0, stream>>>(h2, gid, Wr1, br1, Wr2, br2, out);
}

// Round 14
// 206.094 us; speedup vs baseline: 1.5343x; 1.0288x over previous
//
#include <hip/hip_runtime.h>

typedef __attribute__((ext_vector_type(8))) short bf16x8;
typedef __attribute__((ext_vector_type(4))) float f32x4;

#define N_NODES 10000
#define N_EDGES 320000
#define DIM_IN  256
#define DD      128
#define HH      4
#define HD      512
#define GG      64

// ---------------- CSR build ----------------
__global__ void hist_kernel(const int* __restrict__ dst, int* __restrict__ cnt) {
  int e = blockIdx.x * 256 + threadIdx.x;
  atomicAdd(&cnt[dst[e]], 1);
}

__global__ void scan_kernel(const int* __restrict__ cnt, int* __restrict__ row_off) {
  __shared__ int part[1024];
  int t = threadIdx.x;
  int base = t * 10;
  int s = 0;
#pragma unroll
  for (int i = 0; i < 10; i++) { int idx = base + i; if (idx < N_NODES) s += cnt[idx]; }
  part[t] = s;
  __syncthreads();
  for (int off = 1; off < 1024; off <<= 1) {
    int v = (t >= off) ? part[t - off] : 0;
    __syncthreads();
    part[t] += v;
    __syncthreads();
  }
  int run = part[t] - s;
  for (int i = 0; i < 10; i++) {
    int idx = base + i;
    if (idx < N_NODES) { row_off[idx] = run; run += cnt[idx]; }
  }
  if (t == 1023) row_off[N_NODES] = part[1023];
}

__global__ void scatter_kernel(const int* __restrict__ src, const int* __restrict__ dst,
                               const int* __restrict__ row_off,
                               int* __restrict__ fill, int* __restrict__ srcl) {
  int e = blockIdx.x * 256 + threadIdx.x;
  int d = dst[e];
  int pos = row_off[d] + atomicAdd(&fill[d], 1);
  srcl[pos] = src[e];
}

// ---------------- split-precision helpers ----------------
__device__ inline void split4(float4 v, ushort4& h, ushort4& l) {
  uint bx = __float_as_uint(v.x), by = __float_as_uint(v.y);
  uint bz = __float_as_uint(v.z), bw = __float_as_uint(v.w);
  float rx = v.x - __uint_as_float(bx & 0xFFFF0000u);
  float ry = v.y - __uint_as_float(by & 0xFFFF0000u);
  float rz = v.z - __uint_as_float(bz & 0xFFFF0000u);
  float rw = v.w - __uint_as_float(bw & 0xFFFF0000u);
  h.x = (unsigned short)(bx >> 16); h.y = (unsigned short)(by >> 16);
  h.z = (unsigned short)(bz >> 16); h.w = (unsigned short)(bw >> 16);
  l.x = (unsigned short)(__float_as_uint(rx) >> 16);
  l.y = (unsigned short)(__float_as_uint(ry) >> 16);
  l.z = (unsigned short)(__float_as_uint(rz) >> 16);
  l.w = (unsigned short)(__float_as_uint(rw) >> 16);
}

// row-major fp32 [M][K] -> bf16 hi/lo [M][K]
__global__ __launch_bounds__(256) void split_rm(const float* __restrict__ in,
                                                ushort* __restrict__ oh,
                                                ushort* __restrict__ ol, int n4) {
  int i = blockIdx.x * 256 + threadIdx.x;
  if (i >= n4) return;
  float4 v = ((const float4*)in)[i];
  ushort4 h, l;
  split4(v, h, l);
  ((ushort4*)oh)[i] = h;
  ((ushort4*)ol)[i] = l;
}

// two fp32 [K][N] -> bf16 hi/lo transposed [N][K]; blockIdx.y selects matrix
__global__ __launch_bounds__(256) void split_tr2(
    const float* __restrict__ in0, ushort* __restrict__ oh0, ushort* __restrict__ ol0,
    const float* __restrict__ in1, ushort* __restrict__ oh1, ushort* __restrict__ ol1,
    int K, int N, int lgN) {
  const float* in = blockIdx.y ? in1 : in0;
  ushort* oh = blockIdx.y ? oh1 : oh0;
  ushort* ol = blockIdx.y ? ol1 : ol0;
  int id = blockIdx.x * 256 + threadIdx.x;
  int n = id & (N - 1);
  int kq = id >> lgN;
  if (kq >= (K >> 2)) return;
  int k = kq * 4;
  float4 v;
  v.x = in[(size_t)(k + 0) * N + n];
  v.y = in[(size_t)(k + 1) * N + n];
  v.z = in[(size_t)(k + 2) * N + n];
  v.w = in[(size_t)(k + 3) * N + n];
  ushort4 h, l;
  split4(v, h, l);
  *(ushort4*)(oh + (size_t)n * K + k) = h;
  *(ushort4*)(ol + (size_t)n * K + k) = l;
}

// ---------------- dual GEMM via bf16x3 MFMA (register-prefetch pipelined) ------
template <int K, int NCOL>
__global__ __launch_bounds__(256) void dual_gemm_mfma(
    const ushort* __restrict__ Ahg, const ushort* __restrict__ Alg,
    const ushort* __restrict__ B1hg, const ushort* __restrict__ B1lg,
    const float* __restrict__ bias1,
    const ushort* __restrict__ B2hg, const ushort* __restrict__ B2lg,
    const float* __restrict__ bias2,
    float* __restrict__ C1, float* __restrict__ C2, int M) {
  __shared__ ushort Ah[64][40], Al[64][40];
  __shared__ ushort B1h[64][40], B1l[64][40], B2h[64][40], B2l[64][40];
  int t = threadIdx.x;
  int lane = t & 63, wv = t >> 6;
  int wr = wv >> 1, wc = wv & 1;
  int l15 = lane & 15, l16 = lane >> 4;
  int col0 = blockIdx.x * 64, m0 = blockIdx.y * 64;

  int sr = t >> 2;           // staging row (A) / col (B): 0..63
  int sk = (t & 3) * 8;      // staging k offset: 0,8,16,24
  bool arow_ok = (m0 + sr) < M;
  const ushort* pAh = Ahg + (size_t)(m0 + sr) * K + sk;
  const ushort* pAl = Alg + (size_t)(m0 + sr) * K + sk;
  const ushort* pB1h = B1hg + (size_t)(col0 + sr) * K + sk;
  const ushort* pB1l = B1lg + (size_t)(col0 + sr) * K + sk;
  const ushort* pB2h = B2hg + (size_t)(col0 + sr) * K + sk;
  const ushort* pB2l = B2lg + (size_t)(col0 + sr) * K + sk;

  f32x4 zero = {0.f, 0.f, 0.f, 0.f};
  f32x4 acc1[2][2], acc2[2][2];
#pragma unroll
  for (int i = 0; i < 2; i++)
#pragma unroll
    for (int j = 0; j < 2; j++) { acc1[i][j] = zero; acc2[i][j] = zero; }

  uint4 vah, val, v1h, v1l, v2h, v2l;
#define LOADK(KO)                                                            \
  vah = arow_ok ? *(const uint4*)(pAh + (KO)) : make_uint4(0u, 0u, 0u, 0u);  \
  val = arow_ok ? *(const uint4*)(pAl + (KO)) : make_uint4(0u, 0u, 0u, 0u);  \
  v1h = *(const uint4*)(pB1h + (KO));                                        \
  v1l = *(const uint4*)(pB1l + (KO));                                        \
  v2h = *(const uint4*)(pB2h + (KO));                                        \
  v2l = *(const uint4*)(pB2l + (KO));
  LOADK(0)
  for (int k0 = 0; k0 < K; k0 += 32) {
    __syncthreads();
    *(uint4*)&Ah[sr][sk] = vah;
    *(uint4*)&Al[sr][sk] = val;
    *(uint4*)&B1h[sr][sk] = v1h;
    *(uint4*)&B1l[sr][sk] = v1l;
    *(uint4*)&B2h[sr][sk] = v2h;
    *(uint4*)&B2l[sr][sk] = v2l;
    __syncthreads();
    if (k0 + 32 < K) { LOADK(k0 + 32) }   // issue next-tile loads before MFMA
#pragma unroll
    for (int cb = 0; cb < 2; cb++) {
      int bc = wc * 32 + cb * 16 + l15;
      bf16x8 b1hf = *(const bf16x8*)&B1h[bc][l16 * 8];
      bf16x8 b1lf = *(const bf16x8*)&B1l[bc][l16 * 8];
      bf16x8 b2hf = *(const bf16x8*)&B2h[bc][l16 * 8];
      bf16x8 b2lf = *(const bf16x8*)&B2l[bc][l16 * 8];
#pragma unroll
      for (int rb = 0; rb < 2; rb++) {
        int arw = wr * 32 + rb * 16 + l15;
        bf16x8 ahf = *(const bf16x8*)&Ah[arw][l16 * 8];
        bf16x8 alf = *(const bf16x8*)&Al[arw][l16 * 8];
        acc1[rb][cb] = __builtin_amdgcn_mfma_f32_16x16x32_bf16(ahf, b1hf, acc1[rb][cb], 0, 0, 0);
        acc1[rb][cb] = __builtin_amdgcn_mfma_f32_16x16x32_bf16(ahf, b1lf, acc1[rb][cb], 0, 0, 0);
        acc1[rb][cb] = __builtin_amdgcn_mfma_f32_16x16x32_bf16(alf, b1hf, acc1[rb][cb], 0, 0, 0);
        acc2[rb][cb] = __builtin_amdgcn_mfma_f32_16x16x32_bf16(ahf, b2hf, acc2[rb][cb], 0, 0, 0);
        acc2[rb][cb] = __builtin_amdgcn_mfma_f32_16x16x32_bf16(ahf, b2lf, acc2[rb][cb], 0, 0, 0);
        acc2[rb][cb] = __builtin_amdgcn_mfma_f32_16x16x32_bf16(alf, b2hf, acc2[rb][cb], 0, 0, 0);
      }
    }
  }
#undef LOADK
#pragma unroll
  for (int rb = 0; rb < 2; rb++) {
#pragma unroll
    for (int cb = 0; cb < 2; cb++) {
      int row = m0 + wr * 32 + rb * 16 + l16 * 4;
      int col = col0 + wc * 32 + cb * 16 + l15;
      float bb1 = bias1[col], bb2 = bias2[col];
#pragma unroll
      for (int rr = 0; rr < 4; rr++) {
        if (row + rr < M) {
          C1[(size_t)(row + rr) * NCOL + col] = acc1[rb][cb][rr] + bb1;
          C2[(size_t)(row + rr) * NCOL + col] = acc2[rb][cb][rr] + bb2;
        }
      }
    }
  }
}

// ---------------- layer 1 fused: XCD-pinned head-slices, 4 edges per step ------
// One wave per block (64 thr, grid 4N): block b -> slice = b & 3, node = b >> 2.
// Wave = 4 x 16-lane groups; group owns one edge; lane covers 8 floats.
// leaky(x) = 0.6x + 0.4|x| -> add + 2 fma (abs is a free VOP3 modifier).
// EXEC-SAFETY: all __shfl on myidx execute unconditionally (clamped index).
__global__ __launch_bounds__(64) void fused_gat1(
    const float* __restrict__ hs, const float* __restrict__ hd,
    const float* __restrict__ attn, const int* __restrict__ row_off,
    const int* __restrict__ srcl,
    ushort* __restrict__ outh, ushort* __restrict__ outl) {
  int lane = threadIdx.x;
  int slice = blockIdx.x & 3;
  int v = blockIdx.x >> 2;
  int grp = lane >> 4, sl = lane & 15;
  int off = slice * 128 + sl * 8;
  int start = row_off[v];
  int deg = row_off[v + 1] - start;

  const float* ap = attn + off;
  const float* hp = hd + (size_t)v * HD + off;
  float4 a0 = *(const float4*)ap, a1 = *(const float4*)(ap + 4);
  float4 g0 = *(const float4*)hp, g1 = *(const float4*)(hp + 4);
  float areg[8] = {a0.x, a0.y, a0.z, a0.w, a1.x, a1.y, a1.z, a1.w};
  float hdreg[8] = {g0.x, g0.y, g0.z, g0.w, g1.x, g1.y, g1.z, g1.w};
  float a6[8], a4[8];
#pragma unroll
  for (int j = 0; j < 8; j++) { a6[j] = 0.6f * areg[j]; a4[j] = 0.4f * areg[j]; }
  const float* hsl = hs + off;

  float ssum = 0.f;
  float acc[8] = {0.f, 0.f, 0.f, 0.f, 0.f, 0.f, 0.f, 0.f};

  for (int base = 0; base < deg; base += 64) {
    int nc = deg - base; nc = nc < 64 ? nc : 64;
    // one coalesced index load per 64-edge chunk
    int myidx = (lane < nc) ? srcl[start + base + lane] : 0;

    // 2-deep pipeline: buffer A = edges i0+grp, buffer B = edges i0+4+grp
    float4 cAa = {0,0,0,0}, cAb = {0,0,0,0}, cBa = {0,0,0,0}, cBb = {0,0,0,0};
    {
      int eA = grp, eB = grp + 4;
      int idxA = __shfl(myidx, eA < nc ? eA : 0);   // unconditional shfl
      int idxB = __shfl(myidx, eB < nc ? eB : 0);   // unconditional shfl
      if (eA < nc) { const float* p = hsl + (size_t)idxA * HD; cAa = *(const float4*)p; cAb = *(const float4*)(p + 4); }
      if (eB < nc) { const float* p = hsl + (size_t)idxB * HD; cBa = *(const float4*)p; cBb = *(const float4*)(p + 4); }
    }

    for (int i0 = 0; i0 < nc; i0 += 8) {
#define GAT1_STEP(S, CA, CB)                                                   \
      { int e = i0 + 4 * S + grp;                                              \
        int nx = i0 + 8 + 4 * S + grp;                                         \
        int nidx = __shfl(myidx, nx < nc ? nx : 0);  /* unconditional shfl */  \
        bool vld = e < nc;                                                     \
        float u[8] = {CA.x, CA.y, CA.z, CA.w, CB.x, CB.y, CB.z, CB.w};         \
        if (nx < nc) {                                                         \
          const float* p = hsl + (size_t)nidx * HD;                            \
          CA = *(const float4*)p; CB = *(const float4*)(p + 4);                \
        }                                                                      \
        float part = 0.f;                                                      \
        _Pragma("unroll")                                                      \
        for (int j = 0; j < 8; j++) {                                          \
          float ee = u[j] + hdreg[j];                                          \
          part = fmaf(ee, a6[j], part);                                        \
          part = fmaf(fabsf(ee), a4[j], part);                                 \
        }                                                                      \
        _Pragma("unroll")                                                      \
        for (int k = 1; k < 16; k <<= 1) part += __shfl_xor(part, k);          \
        float wg = vld ? __expf(part) : 0.f;                                   \
        ssum += wg;                                                            \
        _Pragma("unroll")                                                      \
        for (int j = 0; j < 8; j++) acc[j] = fmaf(wg, u[j], acc[j]);           \
      }
      GAT1_STEP(0, cAa, cAb)
      GAT1_STEP(1, cBa, cBb)
#undef GAT1_STEP
    }
  }
  // merge the 4 groups
#pragma unroll
  for (int j = 0; j < 8; j++) {
    acc[j] += __shfl_xor(acc[j], 16);
    acc[j] += __shfl_xor(acc[j], 32);
  }
  ssum += __shfl_xor(ssum, 16);
  ssum += __shfl_xor(ssum, 32);
  if (lane < 16) {
    float inv = ssum > 0.f ? 1.f / ssum : 0.f;
    float4 o0 = make_float4(acc[0] * inv, acc[1] * inv, acc[2] * inv, acc[3] * inv);
    float4 o1 = make_float4(acc[4] * inv, acc[5] * inv, acc[6] * inv, acc[7] * inv);
    ushort4 hv0, lv0, hv1, lv1;
    split4(o0, hv0, lv0);
    split4(o1, hv1, lv1);
    *(ushort4*)(outh + (size_t)v * HD + off) = hv0;
    *(ushort4*)(outh + (size_t)v * HD + off + 4) = hv1;
    *(ushort4*)(outl + (size_t)v * HD + off) = lv0;
    *(ushort4*)(outl + (size_t)v * HD + off + 4) = lv1;
  }
}

// ---------------- layer 2 fused: one wave per node, 4 x 16-lane groups, 2-deep -
__global__ __launch_bounds__(64) void fused_gat2(
    const float* __restrict__ hs, const float* __restrict__ hd,
    const float* __restrict__ attn, const int* __restrict__ row_off,
    const int* __restrict__ srcl, float* __restrict__ out) {
  int lane = threadIdx.x, grp = lane >> 4, sl = lane & 15;
  int v = blockIdx.x;
  int start = row_off[v];
  int deg = row_off[v + 1] - start;

  const float* ap = attn + sl * 8;
  const float* hp = hd + (size_t)v * DD + sl * 8;
  float4 a0 = *(const float4*)ap, a1 = *(const float4*)(ap + 4);
  float4 g0 = *(const float4*)hp, g1 = *(const float4*)(hp + 4);
  float areg[8] = {a0.x, a0.y, a0.z, a0.w, a1.x, a1.y, a1.z, a1.w};
  float hdreg[8] = {g0.x, g0.y, g0.z, g0.w, g1.x, g1.y, g1.z, g1.w};
  float a6[8], a4[8];
#pragma unroll
  for (int j = 0; j < 8; j++) { a6[j] = 0.6f * areg[j]; a4[j] = 0.4f * areg[j]; }
  const float* hsl = hs + sl * 8;

  float ssum = 0.f;
  float acc[8] = {0.f, 0.f, 0.f, 0.f, 0.f, 0.f, 0.f, 0.f};

  float4 c0a = {0,0,0,0}, c0b = {0,0,0,0}, c1a = {0,0,0,0}, c1b = {0,0,0,0};
  if (grp < deg) { const float* p = hsl + (size_t)srcl[start + grp] * DD; c0a = *(const float4*)p; c0b = *(const float4*)(p + 4); }
  if (grp + 4 < deg) { const float* p = hsl + (size_t)srcl[start + grp + 4] * DD; c1a = *(const float4*)p; c1b = *(const float4*)(p + 4); }

  for (int i = grp; i < deg; i += 8) {
    float u0[8] = {c0a.x, c0a.y, c0a.z, c0a.w, c0b.x, c0b.y, c0b.z, c0b.w};
    float u1[8] = {c1a.x, c1a.y, c1a.z, c1a.w, c1b.x, c1b.y, c1b.z, c1b.w};
    bool have1 = (i + 4) < deg;
    if (i + 8 < deg) { const float* p = hsl + (size_t)srcl[start + i + 8] * DD; c0a = *(const float4*)p; c0b = *(const float4*)(p + 4); }
    if (i + 12 < deg) { const float* p = hsl + (size_t)srcl[start + i + 12] * DD; c1a = *(const float4*)p; c1b = *(const float4*)(p + 4); }
    float part0 = 0.f, part1 = 0.f;
#pragma unroll
    for (int j = 0; j < 8; j++) {
      float e0 = u0[j] + hdreg[j];
      part0 = fmaf(e0, a6[j], part0);
      part0 = fmaf(fabsf(e0), a4[j], part0);
      float e1 = u1[j] + hdreg[j];
      part1 = fmaf(e1, a6[j], part1);
      part1 = fmaf(fabsf(e1), a4[j], part1);
    }
#pragma unroll
    for (int k = 1; k < 16; k <<= 1) {
      part0 += __shfl_xor(part0, k);
      part1 += __shfl_xor(part1, k);
    }
    float wg0 = __expf(part0);
    float wg1 = have1 ? __expf(part1) : 0.f;
    ssum += wg0 + wg1;
#pragma unroll
    for (int j = 0; j < 8; j++)
      acc[j] = fmaf(wg0, u0[j], fmaf(wg1, u1[j], acc[j]));
  }
#pragma unroll
  for (int j = 0; j < 8; j++) {
    acc[j] += __shfl_xor(acc[j], 16);
    acc[j] += __shfl_xor(acc[j], 32);
  }
  ssum += __shfl_xor(ssum, 16);
  ssum += __shfl_xor(ssum, 32);
  float inv = ssum > 0.f ? 1.f / ssum : 0.f;
  if (lane < 16) {
    float* op = out + (size_t)v * DD + sl * 8;
    *(float4*)op = make_float4(acc[0] * inv, acc[1] * inv, acc[2] * inv, acc[3] * inv);
    *(float4*)(op + 4) = make_float4(acc[4] * inv, acc[5] * inv, acc[6] * inv, acc[7] * inv);
  }
}

// ---------------- pooling (binary search on sorted gid) + readout MLP ----------
__global__ __launch_bounds__(128) void final_kernel(
    const float* __restrict__ h2, const int* __restrict__ gid,
    const float* __restrict__ Wr1, const float* __restrict__ br1,
    const float* __restrict__ Wr2, const float* __restrict__ br2,
    float* __restrict__ out) {
  int g = blockIdx.x, t = threadIdx.x;
  int a, b;
  { int l = 0, h = N_NODES; while (l < h) { int m = (l + h) >> 1; if (gid[m] < g) l = m + 1; else h = m; } a = l; }
  { int l = a, h = N_NODES; while (l < h) { int m = (l + h) >> 1; if (gid[m] < g + 1) l = m + 1; else h = m; } b = l; }
  float s0 = 0.f, s1 = 0.f, s2 = 0.f, s3 = 0.f;
  int v = a;
  for (; v + 3 < b; v += 4) {
    s0 += h2[(size_t)(v + 0) * DD + t];
    s1 += h2[(size_t)(v + 1) * DD + t];
    s2 += h2[(size_t)(v + 2) * DD + t];
    s3 += h2[(size_t)(v + 3) * DD + t];
  }
  for (; v < b; v++) s0 += h2[(size_t)v * DD + t];
  __shared__ float hgn[128];
  float cnt = (float)(b - a);
  hgn[t] = ((s0 + s1) + (s2 + s3)) / fmaxf(cnt, 1.f);
  __syncthreads();
  if (t < 64) {
    float r = br1[t];
#pragma unroll 8
    for (int k = 0; k < 128; k++) r = fmaf(hgn[k], Wr1[k * 64 + t], r);
    r = fmaxf(r, 0.f);
    float p = r * Wr2[t];
#pragma unroll
    for (int k = 1; k < 64; k <<= 1) p += __shfl_xor(p, k);
    if (t == 0) out[g] = p + br2[0];
  }
}

extern "C" void kernel_launch(void* const* d_in, const int* in_sizes, int n_in,
                              void* d_out, int out_size, void* d_ws, size_t ws_size,
                              hipStream_t stream) {
  (void)in_sizes; (void)n_in; (void)out_size; (void)ws_size;
  const float* x     = (const float*)d_in[0];
  const float* W1s   = (const float*)d_in[1];
  const float* b1s   = (const float*)d_in[2];
  const float* W1d   = (const float*)d_in[3];
  const float* b1d   = (const float*)d_in[4];
  const float* attn1 = (const float*)d_in[5];
  const float* W2s   = (const float*)d_in[6];
  const float* b2s   = (const float*)d_in[7];
  const float* W2d   = (const float*)d_in[8];
  const float* b2d   = (const float*)d_in[9];
  const float* attn2 = (const float*)d_in[10];
  const float* Wr1   = (const float*)d_in[11];
  const float* br1   = (const float*)d_in[12];
  const float* Wr2   = (const float*)d_in[13];
  const float* br2   = (const float*)d_in[14];
  const int* src     = (const int*)d_in[15];
  const int* dst     = (const int*)d_in[16];
  const int* gid     = (const int*)d_in[17];
  float* out = (float*)d_out;

  char* ws = (char*)d_ws;
  float*  hs1     = (float*)(ws + 0);           // [10000][512] f32 (20.48 MB)
  float*  hd1     = (float*)(ws + 20480000);    // [10000][512] f32
  ushort* h1h     = (ushort*)(ws + 40960000);   // [10000][512] bf16 (10.24 MB)
  ushort* h1l     = (ushort*)(ws + 51200000);   // 10.24 MB
  ushort* xh      = (ushort*)(ws + 61440000);   // [10000][256] bf16 (5.12 MB)
  ushort* xl      = (ushort*)(ws + 66560000);   // 5.12 MB
  int*    srcl    = (int*)(ws + 71680000);      // E int (1.28 MB)
  int*    row_off = (int*)(ws + 72960000);      // N+1
  int*    cnt     = (int*)(ws + 73000064);      // N
  int*    fill    = (int*)(ws + 73040064);      // N
  ushort* b1sh    = (ushort*)(ws + 73080064);   // [512][256] bf16 (0.26 MB)
  ushort* b1sl    = (ushort*)(ws + 73342208);
  ushort* b1dh    = (ushort*)(ws + 73604352);
  ushort* b1dl    = (ushort*)(ws + 73866496);
  ushort* b2sh    = (ushort*)(ws + 74128640);   // [128][512] bf16 (0.13 MB)
  ushort* b2sl    = (ushort*)(ws + 74259712);
  ushort* b2dh    = (ushort*)(ws + 74390784);
  ushort* b2dl    = (ushort*)(ws + 74521856);
  // layer-2 reuse (hs1/hd1 regions are dead after gat1; h1h/h1l dead after gemm2)
  float*  hs2     = (float*)(ws + 0);           // [10000][128] f32 (5.12 MB)
  float*  hd2     = (float*)(ws + 5120000);
  float*  h2      = (float*)(ws + 40960000);    // over h1h after gemm2 done

  hipMemsetAsync(cnt, 0, 2 * N_NODES * 4, stream);

  hist_kernel<<<N_EDGES / 256, 256, 0, stream>>>(dst, cnt);
  scan_kernel<<<1, 1024, 0, stream>>>(cnt, row_off);
  scatter_kernel<<<N_EDGES / 256, 256, 0, stream>>>(src, dst, row_off, fill, srcl);

  // preconvert: x and weights
  split_rm<<<(N_NODES * DIM_IN / 4 + 255) / 256, 256, 0, stream>>>(x, xh, xl, N_NODES * DIM_IN / 4);
  split_tr2<<<dim3((HD * (DIM_IN / 4) + 255) / 256, 2), 256, 0, stream>>>(
      W1s, b1sh, b1sl, W1d, b1dh, b1dl, DIM_IN, HD, 9);
  split_tr2<<<dim3((DD * (HD / 4) + 255) / 256, 2), 256, 0, stream>>>(
      W2s, b2sh, b2sl, W2d, b2dh, b2dl, HD, DD, 7);

  dual_gemm_mfma<DIM_IN, HD><<<dim3(HD / 64, (N_NODES + 63) / 64), 256, 0, stream>>>(
      xh, xl, b1sh, b1sl, b1s, b1dh, b1dl, b1d, hs1, hd1, N_NODES);
  fused_gat1<<<4 * N_NODES, 64, 0, stream>>>(hs1, hd1, attn1, row_off, srcl, h1h, h1l);

  dual_gemm_mfma<HD, DD><<<dim3(DD / 64, (N_NODES + 63) / 64), 256, 0, stream>>>(
      h1h, h1l, b2sh, b2sl, b2s, b2dh, b2dl, b2d, hs2, hd2, N_NODES);
  fused_gat2<<<N_NODES, 64, 0, stream>>>(hs2, hd2, attn2, row_off, srcl, h2);

  final_kernel<<<GG, 128, 0, stream>>>(h2, gid, Wr1, br1, Wr2, br2, out);
}